// Round 7
// baseline (535.098 us; speedup 1.0000x reference)
//
#include <hip/hip_runtime.h>
#include <math.h>

#define D_MODEL   512
#define D_INNER   1024
#define NHEADS    16
#define HEADDIM   64
#define D_STATE   64
#define D_CONV    7
#define D_FF      2048
#define CONV_DIM  1152
#define D_IN_PROJ 2208
#define BATCH     4
#define SEQLEN    2048
#define NTOK      (BATCH*SEQLEN)
#define EPS       1e-5f

// ---- workspace layout (float32 units) ----  (see R5/R6 journal)
#define OFF_XBCB  9043968ull
#define OFF_XT    13762560ull
#define OFF_YFW   17956864ull
#define OFF_YBW   26345472ull
#define OFF_SREG  34734080ull

typedef __bf16 bf16x8 __attribute__((ext_vector_type(8)));
typedef float  f32x4  __attribute__((ext_vector_type(4)));

__device__ __forceinline__ float siluf(float x) { return x / (1.f + expf(-x)); }
__device__ __forceinline__ float geluf(float x) { return 0.5f * x * (1.f + erff(x * 0.70710678118654752f)); }
__device__ __forceinline__ float softplusf(float x) { return fmaxf(x, 0.f) + log1pf(expf(-fabsf(x))); }
__device__ __forceinline__ int tglob(int d, int c, int t) { int s = c * 64 + t; return d ? (SEQLEN - 1 - s) : s; }
__device__ __forceinline__ unsigned short f2bf(float f) {
    unsigned int u = __float_as_uint(f);
    u += 0x7FFFu + ((u >> 16) & 1u);
    return (unsigned short)(u >> 16);
}
__device__ __forceinline__ float bf2f(unsigned short u) { return __uint_as_float((unsigned)u << 16); }
__device__ __forceinline__ void glds16(const void* g, void* l) {
    __builtin_amdgcn_global_load_lds((const __attribute__((address_space(1))) void*)g,
                                     (__attribute__((address_space(3))) void*)l, 16, 0, 0);
}

// ---------------- LayerNorm -> bf16 ----------------
__global__ __launch_bounds__(256) void ln_kernel(const float* __restrict__ x,
                                                 const float* __restrict__ w,
                                                 const float* __restrict__ b,
                                                 unsigned short* __restrict__ out, int nrows)
{
    int wid = threadIdx.x >> 6;
    int lane = threadIdx.x & 63;
    int row = blockIdx.x * 4 + wid;
    if (row >= nrows) return;
    const float* xr = x + (size_t)row * D_MODEL;
    float4 v0 = *(const float4*)(xr + lane * 8);
    float4 v1 = *(const float4*)(xr + lane * 8 + 4);
    float v[8] = {v0.x, v0.y, v0.z, v0.w, v1.x, v1.y, v1.z, v1.w};
    float s = 0.f;
#pragma unroll
    for (int i = 0; i < 8; i++) s += v[i];
#pragma unroll
    for (int m = 1; m < 64; m <<= 1) s += __shfl_xor(s, m, 64);
    float mu = s * (1.f / D_MODEL);
    float q = 0.f;
#pragma unroll
    for (int i = 0; i < 8; i++) { float dd = v[i] - mu; q += dd * dd; }
#pragma unroll
    for (int m = 1; m < 64; m <<= 1) q += __shfl_xor(q, m, 64);
    float inv = rsqrtf(q * (1.f / D_MODEL) + EPS);
    float4 w0 = *(const float4*)(w + lane * 8);
    float4 w1 = *(const float4*)(w + lane * 8 + 4);
    float4 b0 = *(const float4*)(b + lane * 8);
    float4 b1 = *(const float4*)(b + lane * 8 + 4);
    float o[8];
    o[0] = (v[0]-mu)*inv*w0.x + b0.x; o[1] = (v[1]-mu)*inv*w0.y + b0.y;
    o[2] = (v[2]-mu)*inv*w0.z + b0.z; o[3] = (v[3]-mu)*inv*w0.w + b0.w;
    o[4] = (v[4]-mu)*inv*w1.x + b1.x; o[5] = (v[5]-mu)*inv*w1.y + b1.y;
    o[6] = (v[6]-mu)*inv*w1.z + b1.z; o[7] = (v[7]-mu)*inv*w1.w + b1.w;
    unsigned short* orow = out + (size_t)row * D_MODEL + lane * 8;
    ushort4 p0, p1;
    p0.x = f2bf(o[0]); p0.y = f2bf(o[1]); p0.z = f2bf(o[2]); p0.w = f2bf(o[3]);
    p1.x = f2bf(o[4]); p1.y = f2bf(o[5]); p1.z = f2bf(o[6]); p1.w = f2bf(o[7]);
    *(ushort4*)orow = p0;
    *(ushort4*)(orow + 4) = p1;
}

// ---------------- weight fp32 -> bf16 (zero-pad to dst_n) ----------------
__global__ __launch_bounds__(256) void wconv_kernel(const float* __restrict__ src,
                                                    unsigned short* __restrict__ dst,
                                                    int src_n, int dst_n)
{
    int i = (blockIdx.x * 256 + threadIdx.x) * 4;
    if (i >= dst_n) return;
    ushort4 o;
    if (i < src_n) {
        float4 v = *(const float4*)(src + i);
        o.x = f2bf(v.x); o.y = f2bf(v.y); o.z = f2bf(v.z); o.w = f2bf(v.w);
    } else {
        o.x = o.y = o.z = o.w = 0;
    }
    *(ushort4*)(dst + i) = o;
}

// ---------------- init: dst = src (+ per-col bias) ----------------
__global__ __launch_bounds__(256) void addinit_kernel(float* __restrict__ dst,
                                                      const float* __restrict__ src,
                                                      const float* __restrict__ bias)
{
    int i = (blockIdx.x * 256 + threadIdx.x) * 4;
    float4 v = *(const float4*)(src + i);
    if (bias) {
        int col = i & (D_MODEL - 1);
        v.x += bias[col]; v.y += bias[col + 1]; v.z += bias[col + 2]; v.w += bias[col + 3];
    }
    *(float4*)(dst + i) = v;
}

// ---------------- bf16 MFMA GEMM (m97 structure) ----------------
__global__ __launch_bounds__(256, 2) void gemm_bf16(const unsigned short* __restrict__ A,
                                                    const unsigned short* __restrict__ W,
                                                    int K, int Nreal,
                                                    float* __restrict__ Cf,
                                                    unsigned short* __restrict__ Cb,
                                                    const float* __restrict__ bias,
                                                    const float* __restrict__ res, int act,
                                                    float* __restrict__ dtf)
{
    __shared__ unsigned short As[128 * 32];
    __shared__ unsigned short Ws[128 * 32];
    const int tid = threadIdx.x;
    const int wave = tid >> 6;
    const int lane = tid & 63;
    const int m0 = blockIdx.y * 128;
    const int n0 = blockIdx.x * 128;
    const int wm = (wave & 1) * 64;
    const int wn = (wave >> 1) * 64;

    const size_t gA = (size_t)(m0 + 32 * wave + (lane >> 2)) * K + (lane & 3) * 8;
    const size_t gW = (size_t)(n0 + 32 * wave + (lane >> 2)) * K + (lane & 3) * 8;
    unsigned short* lA = As + wave * 1024 + lane * 8;
    unsigned short* lW = Ws + wave * 1024 + lane * 8;

    const int fr = lane & 15;
    const int fq = (lane >> 4) * 8;
    f32x4 acc[4][4] = {};

    for (int k0 = 0; k0 < K; k0 += 32) {
        glds16(A + gA + k0, lA);
        glds16(A + gA + (size_t)16 * K + k0, lA + 512);
        glds16(W + gW + k0, lW);
        glds16(W + gW + (size_t)16 * K + k0, lW + 512);
        __syncthreads();
        bf16x8 af[4], bf[4];
#pragma unroll
        for (int mi = 0; mi < 4; mi++)
            af[mi] = *(const bf16x8*)(As + (wm + mi * 16 + fr) * 32 + fq);
#pragma unroll
        for (int ni = 0; ni < 4; ni++)
            bf[ni] = *(const bf16x8*)(Ws + (wn + ni * 16 + fr) * 32 + fq);
#pragma unroll
        for (int mi = 0; mi < 4; mi++)
#pragma unroll
            for (int ni = 0; ni < 4; ni++)
                acc[mi][ni] = __builtin_amdgcn_mfma_f32_16x16x32_bf16(af[mi], bf[ni], acc[mi][ni], 0, 0, 0);
        __syncthreads();
    }

    const int colb = n0 + wn + (lane & 15);
    const int rowb = m0 + wm + (lane >> 4) * 4;
#pragma unroll
    for (int mi = 0; mi < 4; mi++) {
#pragma unroll
        for (int ni = 0; ni < 4; ni++) {
            int col = colb + ni * 16;
            if (col < Nreal) {
#pragma unroll
                for (int r = 0; r < 4; r++) {
                    int row = rowb + mi * 16 + r;
                    float v = acc[mi][ni][r];
                    size_t idx = (size_t)row * Nreal + col;
                    if (bias) v += bias[col];
                    if (res) v += res[idx];
                    if (act) v = geluf(v);
                    if (Cb) {
                        Cb[idx] = f2bf(v);
                        if (dtf && col >= 2176) dtf[(size_t)row * 32 + (col - 2176)] = v;
                    } else Cf[idx] = v;
                }
            }
        }
    }
}

// ---------------- split-K bf16 MFMA GEMM: atomically accumulates fp32 ----------------
__global__ __launch_bounds__(256, 2) void gemm_bf16_sk(const unsigned short* __restrict__ A,
                                                       const unsigned short* __restrict__ W,
                                                       int K, int Kc, int Nreal,
                                                       float* __restrict__ Cf)
{
    __shared__ unsigned short As[128 * 32];
    __shared__ unsigned short Ws[128 * 32];
    const int tid = threadIdx.x;
    const int wave = tid >> 6;
    const int lane = tid & 63;
    const int m0 = blockIdx.y * 128;
    const int n0 = blockIdx.x * 128;
    const int kb = blockIdx.z * Kc;
    const int wm = (wave & 1) * 64;
    const int wn = (wave >> 1) * 64;

    const size_t gA = (size_t)(m0 + 32 * wave + (lane >> 2)) * K + (lane & 3) * 8 + kb;
    const size_t gW = (size_t)(n0 + 32 * wave + (lane >> 2)) * K + (lane & 3) * 8 + kb;
    unsigned short* lA = As + wave * 1024 + lane * 8;
    unsigned short* lW = Ws + wave * 1024 + lane * 8;

    const int fr = lane & 15;
    const int fq = (lane >> 4) * 8;
    f32x4 acc[4][4] = {};

    for (int k0 = 0; k0 < Kc; k0 += 32) {
        glds16(A + gA + k0, lA);
        glds16(A + gA + (size_t)16 * K + k0, lA + 512);
        glds16(W + gW + k0, lW);
        glds16(W + gW + (size_t)16 * K + k0, lW + 512);
        __syncthreads();
        bf16x8 af[4], bf[4];
#pragma unroll
        for (int mi = 0; mi < 4; mi++)
            af[mi] = *(const bf16x8*)(As + (wm + mi * 16 + fr) * 32 + fq);
#pragma unroll
        for (int ni = 0; ni < 4; ni++)
            bf[ni] = *(const bf16x8*)(Ws + (wn + ni * 16 + fr) * 32 + fq);
#pragma unroll
        for (int mi = 0; mi < 4; mi++)
#pragma unroll
            for (int ni = 0; ni < 4; ni++)
                acc[mi][ni] = __builtin_amdgcn_mfma_f32_16x16x32_bf16(af[mi], bf[ni], acc[mi][ni], 0, 0, 0);
        __syncthreads();
    }

    const int colb = n0 + wn + (lane & 15);
    const int rowb = m0 + wm + (lane >> 4) * 4;
#pragma unroll
    for (int mi = 0; mi < 4; mi++) {
#pragma unroll
        for (int ni = 0; ni < 4; ni++) {
            int col = colb + ni * 16;
            if (col < Nreal) {
#pragma unroll
                for (int r = 0; r < 4; r++) {
                    int row = rowb + mi * 16 + r;
                    unsafeAtomicAdd(Cf + (size_t)row * Nreal + col, acc[mi][ni][r]);
                }
            }
        }
    }
}

// ---------------- depthwise causal conv (k=7) + bias + SiLU, bf16 in/out ----------------
__global__ __launch_bounds__(256) void conv_kernel(const unsigned short* __restrict__ zx,
                                                   const float* __restrict__ conv_w,
                                                   const float* __restrict__ conv_b,
                                                   unsigned short* __restrict__ out)
{
    int gid = blockIdx.x * 256 + threadIdx.x;
    if (gid >= NTOK * CONV_DIM) return;
    int c = gid % CONV_DIM;
    int bt = gid / CONV_DIM;
    int t = bt & (SEQLEN - 1);
    float acc = conv_b[c];
    const unsigned short* base = zx + (size_t)bt * D_IN_PROJ + D_INNER + c;
#pragma unroll
    for (int j = 0; j < D_CONV; j++) {
        int tt = t - 6 + j;
        if (tt >= 0) acc = fmaf(conv_w[c * D_CONV + j], bf2f(base[(ptrdiff_t)(j - 6) * D_IN_PROJ]), acc);
    }
    out[(size_t)bt * CONV_DIM + c] = f2bf(siluf(acc));
}

// ---------------- transpose xs: xbc_bf[:, :1024] -> xT[b][p][t] ----------------
__global__ __launch_bounds__(256) void xpose_kernel(const unsigned short* __restrict__ xbc,
                                                    unsigned short* __restrict__ xT)
{
    int tt = blockIdx.x, pt = blockIdx.y, b = blockIdx.z;
    __shared__ unsigned short T[64][68];
    {
        int r = threadIdx.x >> 4, q = threadIdx.x & 15;
#pragma unroll
        for (int i = 0; i < 4; i++) {
            int t = tt * 64 + r + i * 16;
            ushort4 v = *(const ushort4*)(xbc + (size_t)(b * SEQLEN + t) * CONV_DIM + pt * 64 + q * 4);
            *(ushort4*)&T[r + i * 16][q * 4] = v;
        }
    }
    __syncthreads();
    {
        int p = threadIdx.x >> 4, tq = threadIdx.x & 15;
#pragma unroll
        for (int i = 0; i < 4; i++) {
            int pp = p + i * 16;
            ushort4 o;
            o.x = T[tq * 4 + 0][pp]; o.y = T[tq * 4 + 1][pp];
            o.z = T[tq * 4 + 2][pp]; o.w = T[tq * 4 + 3][pp];
            *(ushort4*)(xT + ((size_t)b * 1024 + pt * 64 + pp) * 2048 + tt * 64 + tq * 4) = o;
        }
    }
}

// ---------------- dt/cum tables (fp32 dt sidecar) ----------------
__global__ __launch_bounds__(256) void dt_table_kernel(const float* __restrict__ dtf,
                                                       const float* __restrict__ dt_bias,
                                                       const float* __restrict__ A_log,
                                                       float* __restrict__ cum_tab,
                                                       float* __restrict__ dtv_tab)
{
    int wid = blockIdx.x * 4 + (threadIdx.x >> 6);
    int lane = threadIdx.x & 63;
    int c = wid & 31, h = (wid >> 5) & 15, b = (wid >> 9) & 3, d = wid >> 11;
    int tg = tglob(d, c, lane);
    float raw = dtf[(size_t)(b * SEQLEN + tg) * 32 + d * 16 + h] + dt_bias[h];
    float dtv = softplusf(raw);
    float cum = -expf(A_log[h]) * dtv;
#pragma unroll
    for (int off = 1; off < 64; off <<= 1) {
        int src = lane - off;
        float o = __shfl(cum, src < 0 ? 0 : src, 64);
        if (lane >= off) cum += o;
    }
    cum_tab[(size_t)wid * 64 + lane] = cum;
    dtv_tab[(size_t)wid * 64 + lane] = dtv;
}

// ---------------- zero boundary rows ----------------
__global__ __launch_bounds__(256) void bzero_kernel(float* __restrict__ y_fw, float* __restrict__ y_bw)
{
    int b = blockIdx.x >> 1, d = blockIdx.x & 1;
    float* row = d ? (y_bw + (size_t)(b * SEQLEN + SEQLEN - 1) * D_INNER)
                   : (y_fw + (size_t)(b * SEQLEN) * D_INNER);
    *(float4*)(row + threadIdx.x * 4) = make_float4(0.f, 0.f, 0.f, 0.f);
}

// ---------------- K1: intra-chunk, MFMA. block=(d,b,c,hq), 4 heads/block ----------------
__global__ __launch_bounds__(256) void ssd_intra_mfma(const unsigned short* __restrict__ xbc,
                                                      const unsigned short* __restrict__ xT,
                                                      const float* __restrict__ cum_tab,
                                                      const float* __restrict__ dtv_tab,
                                                      float* __restrict__ y_fw,
                                                      float* __restrict__ y_bw)
{
    const int bid = blockIdx.x;
    const int hq = bid & 3, c = (bid >> 2) & 31, b = (bid >> 7) & 3, d = bid >> 9;
    const int tid = threadIdx.x, wave = tid >> 6, lane = tid & 63;

    __shared__ unsigned short BnMt[64 * 80];
    __shared__ unsigned short CnXt[64 * 80];
    __shared__ float Gm[64 * 68];
    __shared__ float cum_l[64], dtv_l[64];

    {
        int s = tid >> 2, nq = (tid & 3) * 16;
        int tg = tglob(d, c, s);
        const unsigned short* row = xbc + (size_t)(b * SEQLEN + tg) * CONV_DIM;
#pragma unroll
        for (int k = 0; k < 16; k += 4) {
            *(ushort4*)&BnMt[s * 80 + nq + k] = *(const ushort4*)(row + 1024 + nq + k);
            *(ushort4*)&CnXt[s * 80 + nq + k] = *(const ushort4*)(row + 1088 + nq + k);
        }
    }
    __syncthreads();
    {
        f32x4 ga[4] = {};
        const int mrow = wave * 16 + (lane & 15);
        const int kq = (lane >> 4) * 8;
#pragma unroll
        for (int k0 = 0; k0 < 64; k0 += 32) {
            bf16x8 afr = *(const bf16x8*)&BnMt[mrow * 80 + k0 + kq];
#pragma unroll
            for (int ni = 0; ni < 4; ni++) {
                bf16x8 bfr = *(const bf16x8*)&CnXt[(ni * 16 + (lane & 15)) * 80 + k0 + kq];
                ga[ni] = __builtin_amdgcn_mfma_f32_16x16x32_bf16(afr, bfr, ga[ni], 0, 0, 0);
            }
        }
        int col = lane & 15, quad = lane >> 4;
#pragma unroll
        for (int ni = 0; ni < 4; ni++)
#pragma unroll
            for (int r = 0; r < 4; r++)
                Gm[(wave * 16 + quad * 4 + r) * 68 + ni * 16 + col] = ga[ni][r];
    }

    for (int hh = 0; hh < 4; hh++) {
        const int h = hq * 4 + hh;
        __syncthreads();
        if (tid < 64) {
            int flat = ((d * 4 + b) * 16 + h) * 32 + c;
            cum_l[tid] = cum_tab[(size_t)flat * 64 + tid];
            dtv_l[tid] = dtv_tab[(size_t)flat * 64 + tid];
        }
        {
            const unsigned short* xrow = xT + ((size_t)b * 1024 + h * 64) * 2048;
            int p = tid >> 4, tq = tid & 15;
#pragma unroll
            for (int pi = 0; pi < 4; pi++, p += 16) {
                if (d == 0) {
                    ushort4 v = *(const ushort4*)(xrow + (size_t)p * 2048 + c * 64 + tq * 4);
                    *(ushort4*)&CnXt[p * 80 + tq * 4] = v;
                } else {
                    int base = SEQLEN - 64 - c * 64;
                    ushort4 v = *(const ushort4*)(xrow + (size_t)p * 2048 + base + (15 - tq) * 4);
                    CnXt[p * 80 + tq * 4 + 0] = v.w;
                    CnXt[p * 80 + tq * 4 + 1] = v.z;
                    CnXt[p * 80 + tq * 4 + 2] = v.y;
                    CnXt[p * 80 + tq * 4 + 3] = v.x;
                }
            }
        }
        __syncthreads();
        {
            int s = tid & 63, tq = tid >> 6;
            float cs = cum_l[s], dv = dtv_l[s];
#pragma unroll
            for (int j = 0; j < 16; j++) {
                int t = tq * 16 + j;
                float g = Gm[s * 68 + t];
                float m = (s <= t) ? g * expf(cum_l[t] - cs) * dv : 0.f;
                BnMt[t * 80 + s] = f2bf(m);
            }
        }
        __syncthreads();
        {
            f32x4 acc[4] = {};
            const int mrow = wave * 16 + (lane & 15);
            const int kq = (lane >> 4) * 8;
#pragma unroll
            for (int k0 = 0; k0 < 64; k0 += 32) {
                bf16x8 afr = *(const bf16x8*)&BnMt[mrow * 80 + k0 + kq];
#pragma unroll
                for (int ni = 0; ni < 4; ni++) {
                    bf16x8 bfr = *(const bf16x8*)&CnXt[(ni * 16 + (lane & 15)) * 80 + k0 + kq];
                    acc[ni] = __builtin_amdgcn_mfma_f32_16x16x32_bf16(afr, bfr, acc[ni], 0, 0, 0);
                }
            }
            float* ybuf = d ? y_bw : y_fw;
            int quad = lane >> 4, col0 = lane & 15;
#pragma unroll
            for (int r = 0; r < 4; r++) {
                int tl = wave * 16 + quad * 4 + r;
                int tg = tglob(d, c, tl);
                int tout = d ? (tg - 1) : (tg + 1);
                if (tout >= 0 && tout < SEQLEN) {
                    float* yp = ybuf + (size_t)(b * SEQLEN + tout) * D_INNER + h * 64;
#pragma unroll
                    for (int ni = 0; ni < 4; ni++)
                        yp[ni * 16 + col0] = acc[ni][r];
                }
            }
        }
    }
}

// ---------------- K2: per-chunk state S'[p][n] -> bf16 tiles ----------------
__global__ __launch_bounds__(256) void ssd_state_kernel(const unsigned short* __restrict__ xbc,
                                                        const float* __restrict__ cum_tab,
                                                        const float* __restrict__ dtv_tab,
                                                        unsigned short* __restrict__ sreg16)
{
    const int flat = blockIdx.x;
    const int c = flat & 31, h = (flat >> 5) & 15, b = (flat >> 9) & 3, d = flat >> 11;
    const int tid = threadIdx.x;
    const int ty = tid >> 4, tx = tid & 15;

    __shared__ float Bm[64][64];
    __shared__ float Xw[64][64];
    __shared__ float cum_l[64], dtv_l[64];

    if (tid < 64) {
        cum_l[tid] = cum_tab[(size_t)flat * 64 + tid];
        dtv_l[tid] = dtv_tab[(size_t)flat * 64 + tid];
    }
    __syncthreads();
    float clast = cum_l[63];
    for (int idx = tid; idx < 1024; idx += 256) {
        int s = idx >> 4, q = idx & 15;
        int tg = tglob(d, c, s);
        const unsigned short* row = xbc + (size_t)(b * SEQLEN + tg) * CONV_DIM;
        ushort4 ub = *(const ushort4*)(row + 1024 + q * 4);
        ushort4 ux = *(const ushort4*)(row + h * 64 + q * 4);
        float w = expf(clast - cum_l[s]) * dtv_l[s];
        Bm[s][q*4+0] = bf2f(ub.x); Bm[s][q*4+1] = bf2f(ub.y);
        Bm[s][q*4+2] = bf2f(ub.z); Bm[s][q*4+3] = bf2f(ub.w);
        Xw[s][q*4+0] = bf2f(ux.x)*w; Xw[s][q*4+1] = bf2f(ux.y)*w;
        Xw[s][q*4+2] = bf2f(ux.z)*w; Xw[s][q*4+3] = bf2f(ux.w)*w;
    }
    __syncthreads();
    float acc[4][4] = {};
    for (int s = 0; s < 64; s++) {
        float4 xv = *(const float4*)&Xw[s][ty * 4];
        float4 bv = *(const float4*)&Bm[s][tx * 4];
        float xx[4] = {xv.x, xv.y, xv.z, xv.w};
        float bb[4] = {bv.x, bv.y, bv.z, bv.w};
#pragma unroll
        for (int i = 0; i < 4; i++)
#pragma unroll
            for (int j = 0; j < 4; j++) acc[i][j] = fmaf(xx[i], bb[j], acc[i][j]);
    }
    unsigned short* st = sreg16 + (size_t)flat * 4096;
#pragma unroll
    for (int i = 0; i < 4; i++) {
        ushort4 o;
        o.x = f2bf(acc[i][0]); o.y = f2bf(acc[i][1]);
        o.z = f2bf(acc[i][2]); o.w = f2bf(acc[i][3]);
        *(ushort4*)&st[(size_t)(ty * 4 + i) * 64 + tx * 4] = o;
    }
}

// ---------------- K3: serial chunk scan, bf16 tiles, fp32 carry, prefetch ----------------
__global__ __launch_bounds__(256) void ssd_chunkscan_kernel(const float* __restrict__ cum_tab,
                                                            unsigned short* __restrict__ sreg16)
{
    const int ps = blockIdx.x & 3;
    const int g  = blockIdx.x >> 2;
    const int tid = threadIdx.x;
    const int base = g * 32;
    const size_t off = (size_t)ps * 1024 + tid * 4;
    float h0 = 0.f, h1 = 0.f, h2 = 0.f, h3 = 0.f;
    ushort4 s = *(ushort4*)(sreg16 + (size_t)base * 4096 + off);
    for (int c = 0; c < 32; c++) {
        int flat = base + c;
        ushort4 snext;
        if (c < 31) snext = *(ushort4*)(sreg16 + (size_t)(flat + 1) * 4096 + off);
        float dec = expf(cum_tab[(size_t)flat * 64 + 63]);
        ushort4 o;
        o.x = f2bf(h0); o.y = f2bf(h1); o.z = f2bf(h2); o.w = f2bf(h3);
        *(ushort4*)(sreg16 + (size_t)flat * 4096 + off) = o;
        h0 = h0 * dec + bf2f(s.x);
        h1 = h1 * dec + bf2f(s.y);
        h2 = h2 * dec + bf2f(s.z);
        h3 = h3 * dec + bf2f(s.w);
        s = snext;
    }
}

// ---------------- K4: inter-chunk, MFMA, natural layouts ----------------
__global__ __launch_bounds__(256) void ssd_inter_mfma(const unsigned short* __restrict__ xbc,
                                                      const float* __restrict__ cum_tab,
                                                      const unsigned short* __restrict__ sreg16,
                                                      float* __restrict__ y_fw,
                                                      float* __restrict__ y_bw)
{
    const int flat = blockIdx.x;
    const int c = flat & 31;
    if (c == 0) return;
    const int h = (flat >> 5) & 15, b = (flat >> 9) & 3, d = flat >> 11;
    const int tid = threadIdx.x, wave = tid >> 6, lane = tid & 63;

    __shared__ unsigned short Cs[64 * 72];
    __shared__ unsigned short Hs[64 * 72];
    __shared__ float cum_l[64];

    if (tid < 64) cum_l[tid] = cum_tab[(size_t)flat * 64 + tid];
    {
        int s = tid >> 2, nq = (tid & 3) * 16;
        int tg = tglob(d, c, s);
        const unsigned short* row = xbc + (size_t)(b * SEQLEN + tg) * CONV_DIM + 1088;
        const unsigned short* st = sreg16 + (size_t)flat * 4096 + s * 64;
#pragma unroll
        for (int k = 0; k < 16; k += 4) {
            *(ushort4*)&Cs[s * 72 + nq + k] = *(const ushort4*)(row + nq + k);
            *(ushort4*)&Hs[s * 72 + nq + k] = *(const ushort4*)(st + nq + k);
        }
    }
    __syncthreads();
    f32x4 acc[4] = {};
    const int fr = lane & 15, kq = (lane >> 4) * 8;
    const int mrow = wave * 16 + fr;
#pragma unroll
    for (int k0 = 0; k0 < 64; k0 += 32) {
        bf16x8 afr = *(const bf16x8*)&Cs[mrow * 72 + k0 + kq];
#pragma unroll
        for (int ni = 0; ni < 4; ni++) {
            bf16x8 bfr = *(const bf16x8*)&Hs[(ni * 16 + fr) * 72 + k0 + kq];
            acc[ni] = __builtin_amdgcn_mfma_f32_16x16x32_bf16(afr, bfr, acc[ni], 0, 0, 0);
        }
    }
    float* ybuf = d ? y_bw : y_fw;
    int quad = lane >> 4, col0 = lane & 15;
#pragma unroll
    for (int r = 0; r < 4; r++) {
        int tl = wave * 16 + quad * 4 + r;
        float a = expf(cum_l[tl]);
        int tg = tglob(d, c, tl);
        int tout = d ? (tg - 1) : (tg + 1);
        if (tout >= 0 && tout < SEQLEN) {
            float* yp = ybuf + (size_t)(b * SEQLEN + tout) * D_INNER + h * 64;
#pragma unroll
            for (int ni = 0; ni < 4; ni++)
                yp[ni * 16 + col0] += acc[ni][r] * a;
        }
    }
}

// ---------------- combine -> bf16 yg ----------------
__global__ __launch_bounds__(256) void combine_kernel(const unsigned short* __restrict__ zx,
                                                      const unsigned short* __restrict__ xbc,
                                                      const float* __restrict__ y_fw,
                                                      const float* __restrict__ y_bw,
                                                      const float* __restrict__ Dp,
                                                      const float* __restrict__ rms_w,
                                                      unsigned short* __restrict__ yg)
{
    int row = blockIdx.x;
    int i = threadIdx.x * 4;
    float4 yf = *(const float4*)(y_fw + (size_t)row * D_INNER + i);
    float4 yb = *(const float4*)(y_bw + (size_t)row * D_INNER + i);
    ushort4 uxs = *(const ushort4*)(xbc + (size_t)row * CONV_DIM + i);
    ushort4 uz  = *(const ushort4*)(zx + (size_t)row * D_IN_PROJ + i);
    float dp = Dp[i >> 6];
    float g[4];
    g[0] = (yf.x + yb.x + bf2f(uxs.x) * dp) * siluf(bf2f(uz.x));
    g[1] = (yf.y + yb.y + bf2f(uxs.y) * dp) * siluf(bf2f(uz.y));
    g[2] = (yf.z + yb.z + bf2f(uxs.z) * dp) * siluf(bf2f(uz.z));
    g[3] = (yf.w + yb.w + bf2f(uxs.w) * dp) * siluf(bf2f(uz.w));
    float ss = g[0]*g[0] + g[1]*g[1] + g[2]*g[2] + g[3]*g[3];
#pragma unroll
    for (int m = 1; m < 64; m <<= 1) ss += __shfl_xor(ss, m, 64);
    __shared__ float red[4];
    if ((threadIdx.x & 63) == 0) red[threadIdx.x >> 6] = ss;
    __syncthreads();
    ss = red[0] + red[1] + red[2] + red[3];
    float scale = rsqrtf(ss * (1.f / D_INNER) + EPS);
    float4 rw = *(const float4*)(rms_w + i);
    ushort4 o;
    o.x = f2bf(g[0] * scale * rw.x); o.y = f2bf(g[1] * scale * rw.y);
    o.z = f2bf(g[2] * scale * rw.z); o.w = f2bf(g[3] * scale * rw.w);
    *(ushort4*)(yg + (size_t)row * D_INNER + i) = o;
}

// ---------------- launch ----------------
extern "C" void kernel_launch(void* const* d_in, const int* in_sizes, int n_in,
                              void* d_out, int out_size, void* d_ws, size_t ws_size,
                              hipStream_t stream)
{
    const float* x         = (const float*)d_in[0];
    const float* ln1_w     = (const float*)d_in[1];
    const float* ln1_b     = (const float*)d_in[2];
    const float* in_proj_w = (const float*)d_in[3];
    const float* conv_w    = (const float*)d_in[4];
    const float* conv_b    = (const float*)d_in[5];
    const float* dt_bias   = (const float*)d_in[6];
    const float* A_log     = (const float*)d_in[7];
    const float* Dp        = (const float*)d_in[8];
    const float* rms_w     = (const float*)d_in[9];
    const float* out_proj_w= (const float*)d_in[10];
    const float* ln2_w     = (const float*)d_in[11];
    const float* ln2_b     = (const float*)d_in[12];
    const float* fc1_w     = (const float*)d_in[13];
    const float* fc1_b     = (const float*)d_in[14];
    const float* fc2_w     = (const float*)d_in[15];
    const float* fc2_b     = (const float*)d_in[16];
    float* out = (float*)d_out;

    float* ws0 = (float*)d_ws;
    unsigned short* zx_bf  = (unsigned short*)ws0;
    unsigned short* xbc_bf = (unsigned short*)(ws0 + OFF_XBCB);
    unsigned short* xT_bf  = (unsigned short*)(ws0 + OFF_XT);
    float* y_fw = ws0 + OFF_YFW;
    float* y_bw = ws0 + OFF_YBW;
    float* sreg = ws0 + OFF_SREG;
    unsigned short* sreg16 = (unsigned short*)sreg;
    unsigned short* hA_bf = (unsigned short*)sreg;
    unsigned short* P     = (unsigned short*)(sreg + 2097152);
    unsigned short* yg_bf = (unsigned short*)(sreg + 2686976);
    float* x_res          = sreg + 6881280;
    unsigned short* f1_bf = (unsigned short*)ws0;
    float* cum_tab = out;
    float* dtv_tab = out + 262144;
    float* dtf     = out + 524288;

    // 1. LN1 -> bf16
    ln_kernel<<<dim3(NTOK / 4), dim3(256), 0, stream>>>(x, ln1_w, ln1_b, hA_bf, NTOK);
    // 2. in_proj -> bf16 zx (+ fp32 dt sidecar)
    wconv_kernel<<<dim3(2304 * 512 / 1024), dim3(256), 0, stream>>>(in_proj_w, P, 2208 * 512, 2304 * 512);
    gemm_bf16<<<dim3(18, 64), dim3(256), 0, stream>>>(hA_bf, P, 512, 2208, nullptr, zx_bf, nullptr, nullptr, 0, dtf);
    // 3. conv
    conv_kernel<<<dim3(NTOK * CONV_DIM / 256), dim3(256), 0, stream>>>(zx_bf, conv_w, conv_b, xbc_bf);
    // 4. transpose
    xpose_kernel<<<dim3(32, 16, 4), dim3(256), 0, stream>>>(xbc_bf, xT_bf);
    // 5. tables + boundary zero
    dt_table_kernel<<<dim3(1024), dim3(256), 0, stream>>>(dtf, dt_bias, A_log, cum_tab, dtv_tab);
    bzero_kernel<<<dim3(8), dim3(256), 0, stream>>>(y_fw, y_bw);
    // 6. SSD
    ssd_intra_mfma<<<dim3(1024), dim3(256), 0, stream>>>(xbc_bf, xT_bf, cum_tab, dtv_tab, y_fw, y_bw);
    ssd_state_kernel<<<dim3(4096), dim3(256), 0, stream>>>(xbc_bf, cum_tab, dtv_tab, sreg16);
    ssd_chunkscan_kernel<<<dim3(512), dim3(256), 0, stream>>>(cum_tab, sreg16);
    ssd_inter_mfma<<<dim3(4096), dim3(256), 0, stream>>>(xbc_bf, cum_tab, sreg16, y_fw, y_bw);
    // 7. combine -> bf16 yg
    combine_kernel<<<dim3(NTOK), dim3(256), 0, stream>>>(zx_bf, xbc_bf, y_fw, y_bw, Dp, rms_w, yg_bf);
    // 8. out_proj split-K: x_res = x, then atomic partials
    addinit_kernel<<<dim3(NTOK * D_MODEL / 1024), dim3(256), 0, stream>>>(x_res, x, nullptr);
    wconv_kernel<<<dim3(512 * 1024 / 1024), dim3(256), 0, stream>>>(out_proj_w, P, 512 * 1024, 512 * 1024);
    gemm_bf16_sk<<<dim3(4, 64, 4), dim3(256), 0, stream>>>(yg_bf, P, 1024, 256, 512, x_res);
    // 9. LN2 -> bf16
    ln_kernel<<<dim3(NTOK / 4), dim3(256), 0, stream>>>(x_res, ln2_w, ln2_b, hA_bf, NTOK);
    // 10. fc1 + bias + GELU -> bf16
    wconv_kernel<<<dim3(2048 * 512 / 1024), dim3(256), 0, stream>>>(fc1_w, P, 2048 * 512, 2048 * 512);
    gemm_bf16<<<dim3(16, 64), dim3(256), 0, stream>>>(hA_bf, P, 512, 2048, nullptr, f1_bf, fc1_b, nullptr, 1, nullptr);
    // 11. fc2 split-K: out = x_res + bias, then atomic partials
    addinit_kernel<<<dim3(NTOK * D_MODEL / 1024), dim3(256), 0, stream>>>(out, x_res, fc2_b);
    wconv_kernel<<<dim3(512 * 2048 / 1024), dim3(256), 0, stream>>>(fc2_w, P, 512 * 2048, 512 * 2048);
    gemm_bf16_sk<<<dim3(4, 64, 4), dim3(256), 0, stream>>>(f1_bf, P, 2048, 512, 512, out);
}

// Round 8
// 456.083 us; speedup vs baseline: 1.1732x; 1.1732x over previous
//
#include <hip/hip_runtime.h>
#include <math.h>

#define D_MODEL   512
#define D_INNER   1024
#define NHEADS    16
#define HEADDIM   64
#define D_STATE   64
#define D_CONV    7
#define D_FF      2048
#define CONV_DIM  1152
#define D_IN_PROJ 2208
#define BATCH     4
#define SEQLEN    2048
#define NTOK      (BATCH*SEQLEN)
#define EPS       1e-5f

// ---- workspace layout (float32 units) ----  (see R5/R6 journal)
#define OFF_XBCB  9043968ull
#define OFF_XT    13762560ull
#define OFF_YFW   17956864ull
#define OFF_YBW   26345472ull
#define OFF_SREG  34734080ull

typedef __bf16 bf16x8 __attribute__((ext_vector_type(8)));
typedef float  f32x4  __attribute__((ext_vector_type(4)));

__device__ __forceinline__ float siluf(float x) { return x / (1.f + expf(-x)); }
__device__ __forceinline__ float geluf(float x) { return 0.5f * x * (1.f + erff(x * 0.70710678118654752f)); }
__device__ __forceinline__ float softplusf(float x) { return fmaxf(x, 0.f) + log1pf(expf(-fabsf(x))); }
__device__ __forceinline__ int tglob(int d, int c, int t) { int s = c * 64 + t; return d ? (SEQLEN - 1 - s) : s; }
__device__ __forceinline__ unsigned short f2bf(float f) {
    unsigned int u = __float_as_uint(f);
    u += 0x7FFFu + ((u >> 16) & 1u);
    return (unsigned short)(u >> 16);
}
__device__ __forceinline__ float bf2f(unsigned short u) { return __uint_as_float((unsigned)u << 16); }
__device__ __forceinline__ void glds16(const void* g, void* l) {
    __builtin_amdgcn_global_load_lds((const __attribute__((address_space(1))) void*)g,
                                     (__attribute__((address_space(3))) void*)l, 16, 0, 0);
}

// ---------------- LayerNorm -> bf16 ----------------
__global__ __launch_bounds__(256) void ln_kernel(const float* __restrict__ x,
                                                 const float* __restrict__ w,
                                                 const float* __restrict__ b,
                                                 unsigned short* __restrict__ out, int nrows)
{
    int wid = threadIdx.x >> 6;
    int lane = threadIdx.x & 63;
    int row = blockIdx.x * 4 + wid;
    if (row >= nrows) return;
    const float* xr = x + (size_t)row * D_MODEL;
    float4 v0 = *(const float4*)(xr + lane * 8);
    float4 v1 = *(const float4*)(xr + lane * 8 + 4);
    float v[8] = {v0.x, v0.y, v0.z, v0.w, v1.x, v1.y, v1.z, v1.w};
    float s = 0.f;
#pragma unroll
    for (int i = 0; i < 8; i++) s += v[i];
#pragma unroll
    for (int m = 1; m < 64; m <<= 1) s += __shfl_xor(s, m, 64);
    float mu = s * (1.f / D_MODEL);
    float q = 0.f;
#pragma unroll
    for (int i = 0; i < 8; i++) { float dd = v[i] - mu; q += dd * dd; }
#pragma unroll
    for (int m = 1; m < 64; m <<= 1) q += __shfl_xor(q, m, 64);
    float inv = rsqrtf(q * (1.f / D_MODEL) + EPS);
    float4 w0 = *(const float4*)(w + lane * 8);
    float4 w1 = *(const float4*)(w + lane * 8 + 4);
    float4 b0 = *(const float4*)(b + lane * 8);
    float4 b1 = *(const float4*)(b + lane * 8 + 4);
    float o[8];
    o[0] = (v[0]-mu)*inv*w0.x + b0.x; o[1] = (v[1]-mu)*inv*w0.y + b0.y;
    o[2] = (v[2]-mu)*inv*w0.z + b0.z; o[3] = (v[3]-mu)*inv*w0.w + b0.w;
    o[4] = (v[4]-mu)*inv*w1.x + b1.x; o[5] = (v[5]-mu)*inv*w1.y + b1.y;
    o[6] = (v[6]-mu)*inv*w1.z + b1.z; o[7] = (v[7]-mu)*inv*w1.w + b1.w;
    unsigned short* orow = out + (size_t)row * D_MODEL + lane * 8;
    ushort4 p0, p1;
    p0.x = f2bf(o[0]); p0.y = f2bf(o[1]); p0.z = f2bf(o[2]); p0.w = f2bf(o[3]);
    p1.x = f2bf(o[4]); p1.y = f2bf(o[5]); p1.z = f2bf(o[6]); p1.w = f2bf(o[7]);
    *(ushort4*)orow = p0;
    *(ushort4*)(orow + 4) = p1;
}

// ---------------- weight fp32 -> bf16 (zero-pad to dst_n) ----------------
__global__ __launch_bounds__(256) void wconv_kernel(const float* __restrict__ src,
                                                    unsigned short* __restrict__ dst,
                                                    int src_n, int dst_n)
{
    int i = (blockIdx.x * 256 + threadIdx.x) * 4;
    if (i >= dst_n) return;
    ushort4 o;
    if (i < src_n) {
        float4 v = *(const float4*)(src + i);
        o.x = f2bf(v.x); o.y = f2bf(v.y); o.z = f2bf(v.z); o.w = f2bf(v.w);
    } else {
        o.x = o.y = o.z = o.w = 0;
    }
    *(ushort4*)(dst + i) = o;
}

// ---------------- bf16 MFMA GEMM (m97 structure; grid x = m-tile for XCD L2 sharing) ----------------
__global__ __launch_bounds__(256, 2) void gemm_bf16(const unsigned short* __restrict__ A,
                                                    const unsigned short* __restrict__ W,
                                                    int K, int Nreal,
                                                    float* __restrict__ Cf,
                                                    unsigned short* __restrict__ Cb,
                                                    const float* __restrict__ bias,
                                                    const float* __restrict__ res, int act,
                                                    float* __restrict__ dtf)
{
    __shared__ unsigned short As[128 * 32];
    __shared__ unsigned short Ws[128 * 32];
    const int tid = threadIdx.x;
    const int wave = tid >> 6;
    const int lane = tid & 63;
    const int m0 = blockIdx.x * 128;   // m fastest: A-sharing blocks land on same XCD
    const int n0 = blockIdx.y * 128;
    const int wm = (wave & 1) * 64;
    const int wn = (wave >> 1) * 64;

    const size_t gA = (size_t)(m0 + 32 * wave + (lane >> 2)) * K + (lane & 3) * 8;
    const size_t gW = (size_t)(n0 + 32 * wave + (lane >> 2)) * K + (lane & 3) * 8;
    unsigned short* lA = As + wave * 1024 + lane * 8;
    unsigned short* lW = Ws + wave * 1024 + lane * 8;

    const int fr = lane & 15;
    const int fq = (lane >> 4) * 8;
    f32x4 acc[4][4] = {};

    for (int k0 = 0; k0 < K; k0 += 32) {
        glds16(A + gA + k0, lA);
        glds16(A + gA + (size_t)16 * K + k0, lA + 512);
        glds16(W + gW + k0, lW);
        glds16(W + gW + (size_t)16 * K + k0, lW + 512);
        __syncthreads();
        bf16x8 af[4], bf[4];
#pragma unroll
        for (int mi = 0; mi < 4; mi++)
            af[mi] = *(const bf16x8*)(As + (wm + mi * 16 + fr) * 32 + fq);
#pragma unroll
        for (int ni = 0; ni < 4; ni++)
            bf[ni] = *(const bf16x8*)(Ws + (wn + ni * 16 + fr) * 32 + fq);
#pragma unroll
        for (int mi = 0; mi < 4; mi++)
#pragma unroll
            for (int ni = 0; ni < 4; ni++)
                acc[mi][ni] = __builtin_amdgcn_mfma_f32_16x16x32_bf16(af[mi], bf[ni], acc[mi][ni], 0, 0, 0);
        __syncthreads();
    }

    const int colb = n0 + wn + (lane & 15);
    const int rowb = m0 + wm + (lane >> 4) * 4;
#pragma unroll
    for (int mi = 0; mi < 4; mi++) {
#pragma unroll
        for (int ni = 0; ni < 4; ni++) {
            int col = colb + ni * 16;
            if (col < Nreal) {
#pragma unroll
                for (int r = 0; r < 4; r++) {
                    int row = rowb + mi * 16 + r;
                    float v = acc[mi][ni][r];
                    size_t idx = (size_t)row * Nreal + col;
                    if (bias) v += bias[col];
                    if (res) v += res[idx];
                    if (act) v = geluf(v);
                    if (Cb) {
                        Cb[idx] = f2bf(v);
                        if (dtf && col >= 2176) dtf[(size_t)row * 32 + (col - 2176)] = v;
                    } else Cf[idx] = v;
                }
            }
        }
    }
}

// ---------------- 64x64-tile bf16 MFMA GEMM for skinny-N tails (4 blocks/CU) ----------------
// grid (M/64, N/64), m fastest. Wave w computes rows w*16..w*16+15 x all 64 cols.
__global__ __launch_bounds__(256) void gemm_bf16_t64(const unsigned short* __restrict__ A,
                                                     const unsigned short* __restrict__ W,
                                                     int K, int N,
                                                     float* __restrict__ Cf,
                                                     const float* __restrict__ bias,
                                                     const float* __restrict__ res)
{
    __shared__ unsigned short As[64 * 32];
    __shared__ unsigned short Ws[64 * 32];
    const int tid = threadIdx.x;
    const int wave = tid >> 6;
    const int lane = tid & 63;
    const int m0 = blockIdx.x * 64;
    const int n0 = blockIdx.y * 64;

    const size_t gA = (size_t)(m0 + (tid >> 2)) * K + (tid & 3) * 8;
    const size_t gW = (size_t)(n0 + (tid >> 2)) * K + (tid & 3) * 8;
    unsigned short* lA = As + tid * 8;
    unsigned short* lW = Ws + tid * 8;

    const int fr = lane & 15;
    const int fq = (lane >> 4) * 8;
    f32x4 acc[4] = {};

    for (int k0 = 0; k0 < K; k0 += 32) {
        glds16(A + gA + k0, lA);
        glds16(W + gW + k0, lW);
        __syncthreads();
        bf16x8 af = *(const bf16x8*)(As + (wave * 16 + fr) * 32 + fq);
#pragma unroll
        for (int ni = 0; ni < 4; ni++) {
            bf16x8 bfr = *(const bf16x8*)(Ws + (ni * 16 + fr) * 32 + fq);
            acc[ni] = __builtin_amdgcn_mfma_f32_16x16x32_bf16(af, bfr, acc[ni], 0, 0, 0);
        }
        __syncthreads();
    }

    const int col0 = n0 + (lane & 15);
    const int rowb = m0 + wave * 16 + (lane >> 4) * 4;
#pragma unroll
    for (int ni = 0; ni < 4; ni++) {
        int col = col0 + ni * 16;
        float bb = bias ? bias[col] : 0.f;
#pragma unroll
        for (int r = 0; r < 4; r++) {
            int row = rowb + r;
            size_t idx = (size_t)row * N + col;
            float v = acc[ni][r] + bb;
            if (res) v += res[idx];
            Cf[idx] = v;
        }
    }
}

// ---------------- depthwise causal conv (k=7) + bias + SiLU, bf16 in/out ----------------
__global__ __launch_bounds__(256) void conv_kernel(const unsigned short* __restrict__ zx,
                                                   const float* __restrict__ conv_w,
                                                   const float* __restrict__ conv_b,
                                                   unsigned short* __restrict__ out)
{
    int gid = blockIdx.x * 256 + threadIdx.x;
    if (gid >= NTOK * CONV_DIM) return;
    int c = gid % CONV_DIM;
    int bt = gid / CONV_DIM;
    int t = bt & (SEQLEN - 1);
    float acc = conv_b[c];
    const unsigned short* base = zx + (size_t)bt * D_IN_PROJ + D_INNER + c;
#pragma unroll
    for (int j = 0; j < D_CONV; j++) {
        int tt = t - 6 + j;
        if (tt >= 0) acc = fmaf(conv_w[c * D_CONV + j], bf2f(base[(ptrdiff_t)(j - 6) * D_IN_PROJ]), acc);
    }
    out[(size_t)bt * CONV_DIM + c] = f2bf(siluf(acc));
}

// ---------------- transpose xs: xbc_bf[:, :1024] -> xT[b][p][t] ----------------
__global__ __launch_bounds__(256) void xpose_kernel(const unsigned short* __restrict__ xbc,
                                                    unsigned short* __restrict__ xT)
{
    int tt = blockIdx.x, pt = blockIdx.y, b = blockIdx.z;
    __shared__ unsigned short T[64][68];
    {
        int r = threadIdx.x >> 4, q = threadIdx.x & 15;
#pragma unroll
        for (int i = 0; i < 4; i++) {
            int t = tt * 64 + r + i * 16;
            ushort4 v = *(const ushort4*)(xbc + (size_t)(b * SEQLEN + t) * CONV_DIM + pt * 64 + q * 4);
            *(ushort4*)&T[r + i * 16][q * 4] = v;
        }
    }
    __syncthreads();
    {
        int p = threadIdx.x >> 4, tq = threadIdx.x & 15;
#pragma unroll
        for (int i = 0; i < 4; i++) {
            int pp = p + i * 16;
            ushort4 o;
            o.x = T[tq * 4 + 0][pp]; o.y = T[tq * 4 + 1][pp];
            o.z = T[tq * 4 + 2][pp]; o.w = T[tq * 4 + 3][pp];
            *(ushort4*)(xT + ((size_t)b * 1024 + pt * 64 + pp) * 2048 + tt * 64 + tq * 4) = o;
        }
    }
}

// ---------------- dt/cum tables (fp32 dt sidecar) ----------------
__global__ __launch_bounds__(256) void dt_table_kernel(const float* __restrict__ dtf,
                                                       const float* __restrict__ dt_bias,
                                                       const float* __restrict__ A_log,
                                                       float* __restrict__ cum_tab,
                                                       float* __restrict__ dtv_tab)
{
    int wid = blockIdx.x * 4 + (threadIdx.x >> 6);
    int lane = threadIdx.x & 63;
    int c = wid & 31, h = (wid >> 5) & 15, b = (wid >> 9) & 3, d = wid >> 11;
    int tg = tglob(d, c, lane);
    float raw = dtf[(size_t)(b * SEQLEN + tg) * 32 + d * 16 + h] + dt_bias[h];
    float dtv = softplusf(raw);
    float cum = -expf(A_log[h]) * dtv;
#pragma unroll
    for (int off = 1; off < 64; off <<= 1) {
        int src = lane - off;
        float o = __shfl(cum, src < 0 ? 0 : src, 64);
        if (lane >= off) cum += o;
    }
    cum_tab[(size_t)wid * 64 + lane] = cum;
    dtv_tab[(size_t)wid * 64 + lane] = dtv;
}

// ---------------- zero boundary rows ----------------
__global__ __launch_bounds__(256) void bzero_kernel(float* __restrict__ y_fw, float* __restrict__ y_bw)
{
    int b = blockIdx.x >> 1, d = blockIdx.x & 1;
    float* row = d ? (y_bw + (size_t)(b * SEQLEN + SEQLEN - 1) * D_INNER)
                   : (y_fw + (size_t)(b * SEQLEN) * D_INNER);
    *(float4*)(row + threadIdx.x * 4) = make_float4(0.f, 0.f, 0.f, 0.f);
}

// ---------------- K1: intra-chunk, MFMA. block=(d,b,c,hq), 4 heads/block ----------------
__global__ __launch_bounds__(256) void ssd_intra_mfma(const unsigned short* __restrict__ xbc,
                                                      const unsigned short* __restrict__ xT,
                                                      const float* __restrict__ cum_tab,
                                                      const float* __restrict__ dtv_tab,
                                                      float* __restrict__ y_fw,
                                                      float* __restrict__ y_bw)
{
    const int bid = blockIdx.x;
    const int hq = bid & 3, c = (bid >> 2) & 31, b = (bid >> 7) & 3, d = bid >> 9;
    const int tid = threadIdx.x, wave = tid >> 6, lane = tid & 63;

    __shared__ unsigned short BnMt[64 * 80];
    __shared__ unsigned short CnXt[64 * 80];
    __shared__ float Gm[64 * 68];
    __shared__ float cum_l[64], dtv_l[64];

    {
        int s = tid >> 2, nq = (tid & 3) * 16;
        int tg = tglob(d, c, s);
        const unsigned short* row = xbc + (size_t)(b * SEQLEN + tg) * CONV_DIM;
#pragma unroll
        for (int k = 0; k < 16; k += 4) {
            *(ushort4*)&BnMt[s * 80 + nq + k] = *(const ushort4*)(row + 1024 + nq + k);
            *(ushort4*)&CnXt[s * 80 + nq + k] = *(const ushort4*)(row + 1088 + nq + k);
        }
    }
    __syncthreads();
    {
        f32x4 ga[4] = {};
        const int mrow = wave * 16 + (lane & 15);
        const int kq = (lane >> 4) * 8;
#pragma unroll
        for (int k0 = 0; k0 < 64; k0 += 32) {
            bf16x8 afr = *(const bf16x8*)&BnMt[mrow * 80 + k0 + kq];
#pragma unroll
            for (int ni = 0; ni < 4; ni++) {
                bf16x8 bfr = *(const bf16x8*)&CnXt[(ni * 16 + (lane & 15)) * 80 + k0 + kq];
                ga[ni] = __builtin_amdgcn_mfma_f32_16x16x32_bf16(afr, bfr, ga[ni], 0, 0, 0);
            }
        }
        int col = lane & 15, quad = lane >> 4;
#pragma unroll
        for (int ni = 0; ni < 4; ni++)
#pragma unroll
            for (int r = 0; r < 4; r++)
                Gm[(wave * 16 + quad * 4 + r) * 68 + ni * 16 + col] = ga[ni][r];
    }

    for (int hh = 0; hh < 4; hh++) {
        const int h = hq * 4 + hh;
        __syncthreads();
        if (tid < 64) {
            int flat = ((d * 4 + b) * 16 + h) * 32 + c;
            cum_l[tid] = cum_tab[(size_t)flat * 64 + tid];
            dtv_l[tid] = dtv_tab[(size_t)flat * 64 + tid];
        }
        {
            const unsigned short* xrow = xT + ((size_t)b * 1024 + h * 64) * 2048;
            int p = tid >> 4, tq = tid & 15;
#pragma unroll
            for (int pi = 0; pi < 4; pi++, p += 16) {
                if (d == 0) {
                    ushort4 v = *(const ushort4*)(xrow + (size_t)p * 2048 + c * 64 + tq * 4);
                    *(ushort4*)&CnXt[p * 80 + tq * 4] = v;
                } else {
                    int base = SEQLEN - 64 - c * 64;
                    ushort4 v = *(const ushort4*)(xrow + (size_t)p * 2048 + base + (15 - tq) * 4);
                    CnXt[p * 80 + tq * 4 + 0] = v.w;
                    CnXt[p * 80 + tq * 4 + 1] = v.z;
                    CnXt[p * 80 + tq * 4 + 2] = v.y;
                    CnXt[p * 80 + tq * 4 + 3] = v.x;
                }
            }
        }
        __syncthreads();
        {
            int s = tid & 63, tq = tid >> 6;
            float cs = cum_l[s], dv = dtv_l[s];
#pragma unroll
            for (int j = 0; j < 16; j++) {
                int t = tq * 16 + j;
                float g = Gm[s * 68 + t];
                float m = (s <= t) ? g * expf(cum_l[t] - cs) * dv : 0.f;
                BnMt[t * 80 + s] = f2bf(m);
            }
        }
        __syncthreads();
        {
            f32x4 acc[4] = {};
            const int mrow = wave * 16 + (lane & 15);
            const int kq = (lane >> 4) * 8;
#pragma unroll
            for (int k0 = 0; k0 < 64; k0 += 32) {
                bf16x8 afr = *(const bf16x8*)&BnMt[mrow * 80 + k0 + kq];
#pragma unroll
                for (int ni = 0; ni < 4; ni++) {
                    bf16x8 bfr = *(const bf16x8*)&CnXt[(ni * 16 + (lane & 15)) * 80 + k0 + kq];
                    acc[ni] = __builtin_amdgcn_mfma_f32_16x16x32_bf16(afr, bfr, acc[ni], 0, 0, 0);
                }
            }
            float* ybuf = d ? y_bw : y_fw;
            int quad = lane >> 4, col0 = lane & 15;
#pragma unroll
            for (int r = 0; r < 4; r++) {
                int tl = wave * 16 + quad * 4 + r;
                int tg = tglob(d, c, tl);
                int tout = d ? (tg - 1) : (tg + 1);
                if (tout >= 0 && tout < SEQLEN) {
                    float* yp = ybuf + (size_t)(b * SEQLEN + tout) * D_INNER + h * 64;
#pragma unroll
                    for (int ni = 0; ni < 4; ni++)
                        yp[ni * 16 + col0] = acc[ni][r];
                }
            }
        }
    }
}

// ---------------- K2: per-chunk state S'[p][n] -> bf16 tiles ----------------
__global__ __launch_bounds__(256) void ssd_state_kernel(const unsigned short* __restrict__ xbc,
                                                        const float* __restrict__ cum_tab,
                                                        const float* __restrict__ dtv_tab,
                                                        unsigned short* __restrict__ sreg16)
{
    const int flat = blockIdx.x;
    const int c = flat & 31, h = (flat >> 5) & 15, b = (flat >> 9) & 3, d = flat >> 11;
    const int tid = threadIdx.x;
    const int ty = tid >> 4, tx = tid & 15;

    __shared__ float Bm[64][64];
    __shared__ float Xw[64][64];
    __shared__ float cum_l[64], dtv_l[64];

    if (tid < 64) {
        cum_l[tid] = cum_tab[(size_t)flat * 64 + tid];
        dtv_l[tid] = dtv_tab[(size_t)flat * 64 + tid];
    }
    __syncthreads();
    float clast = cum_l[63];
    for (int idx = tid; idx < 1024; idx += 256) {
        int s = idx >> 4, q = idx & 15;
        int tg = tglob(d, c, s);
        const unsigned short* row = xbc + (size_t)(b * SEQLEN + tg) * CONV_DIM;
        ushort4 ub = *(const ushort4*)(row + 1024 + q * 4);
        ushort4 ux = *(const ushort4*)(row + h * 64 + q * 4);
        float w = expf(clast - cum_l[s]) * dtv_l[s];
        Bm[s][q*4+0] = bf2f(ub.x); Bm[s][q*4+1] = bf2f(ub.y);
        Bm[s][q*4+2] = bf2f(ub.z); Bm[s][q*4+3] = bf2f(ub.w);
        Xw[s][q*4+0] = bf2f(ux.x)*w; Xw[s][q*4+1] = bf2f(ux.y)*w;
        Xw[s][q*4+2] = bf2f(ux.z)*w; Xw[s][q*4+3] = bf2f(ux.w)*w;
    }
    __syncthreads();
    float acc[4][4] = {};
    for (int s = 0; s < 64; s++) {
        float4 xv = *(const float4*)&Xw[s][ty * 4];
        float4 bv = *(const float4*)&Bm[s][tx * 4];
        float xx[4] = {xv.x, xv.y, xv.z, xv.w};
        float bb[4] = {bv.x, bv.y, bv.z, bv.w};
#pragma unroll
        for (int i = 0; i < 4; i++)
#pragma unroll
            for (int j = 0; j < 4; j++) acc[i][j] = fmaf(xx[i], bb[j], acc[i][j]);
    }
    unsigned short* st = sreg16 + (size_t)flat * 4096;
#pragma unroll
    for (int i = 0; i < 4; i++) {
        ushort4 o;
        o.x = f2bf(acc[i][0]); o.y = f2bf(acc[i][1]);
        o.z = f2bf(acc[i][2]); o.w = f2bf(acc[i][3]);
        *(ushort4*)&st[(size_t)(ty * 4 + i) * 64 + tx * 4] = o;
    }
}

// ---------------- K3: serial chunk scan, bf16 tiles, fp32 carry, prefetch ----------------
__global__ __launch_bounds__(256) void ssd_chunkscan_kernel(const float* __restrict__ cum_tab,
                                                            unsigned short* __restrict__ sreg16)
{
    const int ps = blockIdx.x & 3;
    const int g  = blockIdx.x >> 2;
    const int tid = threadIdx.x;
    const int base = g * 32;
    const size_t off = (size_t)ps * 1024 + tid * 4;
    float h0 = 0.f, h1 = 0.f, h2 = 0.f, h3 = 0.f;
    ushort4 s = *(ushort4*)(sreg16 + (size_t)base * 4096 + off);
    for (int c = 0; c < 32; c++) {
        int flat = base + c;
        ushort4 snext;
        if (c < 31) snext = *(ushort4*)(sreg16 + (size_t)(flat + 1) * 4096 + off);
        float dec = expf(cum_tab[(size_t)flat * 64 + 63]);
        ushort4 o;
        o.x = f2bf(h0); o.y = f2bf(h1); o.z = f2bf(h2); o.w = f2bf(h3);
        *(ushort4*)(sreg16 + (size_t)flat * 4096 + off) = o;
        h0 = h0 * dec + bf2f(s.x);
        h1 = h1 * dec + bf2f(s.y);
        h2 = h2 * dec + bf2f(s.z);
        h3 = h3 * dec + bf2f(s.w);
        s = snext;
    }
}

// ---------------- K4: inter-chunk, MFMA, natural layouts ----------------
__global__ __launch_bounds__(256) void ssd_inter_mfma(const unsigned short* __restrict__ xbc,
                                                      const float* __restrict__ cum_tab,
                                                      const unsigned short* __restrict__ sreg16,
                                                      float* __restrict__ y_fw,
                                                      float* __restrict__ y_bw)
{
    const int flat = blockIdx.x;
    const int c = flat & 31;
    if (c == 0) return;
    const int h = (flat >> 5) & 15, b = (flat >> 9) & 3, d = flat >> 11;
    const int tid = threadIdx.x, wave = tid >> 6, lane = tid & 63;

    __shared__ unsigned short Cs[64 * 72];
    __shared__ unsigned short Hs[64 * 72];
    __shared__ float cum_l[64];

    if (tid < 64) cum_l[tid] = cum_tab[(size_t)flat * 64 + tid];
    {
        int s = tid >> 2, nq = (tid & 3) * 16;
        int tg = tglob(d, c, s);
        const unsigned short* row = xbc + (size_t)(b * SEQLEN + tg) * CONV_DIM + 1088;
        const unsigned short* st = sreg16 + (size_t)flat * 4096 + s * 64;
#pragma unroll
        for (int k = 0; k < 16; k += 4) {
            *(ushort4*)&Cs[s * 72 + nq + k] = *(const ushort4*)(row + nq + k);
            *(ushort4*)&Hs[s * 72 + nq + k] = *(const ushort4*)(st + nq + k);
        }
    }
    __syncthreads();
    f32x4 acc[4] = {};
    const int fr = lane & 15, kq = (lane >> 4) * 8;
    const int mrow = wave * 16 + fr;
#pragma unroll
    for (int k0 = 0; k0 < 64; k0 += 32) {
        bf16x8 afr = *(const bf16x8*)&Cs[mrow * 72 + k0 + kq];
#pragma unroll
        for (int ni = 0; ni < 4; ni++) {
            bf16x8 bfr = *(const bf16x8*)&Hs[(ni * 16 + fr) * 72 + k0 + kq];
            acc[ni] = __builtin_amdgcn_mfma_f32_16x16x32_bf16(afr, bfr, acc[ni], 0, 0, 0);
        }
    }
    float* ybuf = d ? y_bw : y_fw;
    int quad = lane >> 4, col0 = lane & 15;
#pragma unroll
    for (int r = 0; r < 4; r++) {
        int tl = wave * 16 + quad * 4 + r;
        float a = expf(cum_l[tl]);
        int tg = tglob(d, c, tl);
        int tout = d ? (tg - 1) : (tg + 1);
        if (tout >= 0 && tout < SEQLEN) {
            float* yp = ybuf + (size_t)(b * SEQLEN + tout) * D_INNER + h * 64;
#pragma unroll
            for (int ni = 0; ni < 4; ni++)
                yp[ni * 16 + col0] += acc[ni][r] * a;
        }
    }
}

// ---------------- combine -> bf16 yg ----------------
__global__ __launch_bounds__(256) void combine_kernel(const unsigned short* __restrict__ zx,
                                                      const unsigned short* __restrict__ xbc,
                                                      const float* __restrict__ y_fw,
                                                      const float* __restrict__ y_bw,
                                                      const float* __restrict__ Dp,
                                                      const float* __restrict__ rms_w,
                                                      unsigned short* __restrict__ yg)
{
    int row = blockIdx.x;
    int i = threadIdx.x * 4;
    float4 yf = *(const float4*)(y_fw + (size_t)row * D_INNER + i);
    float4 yb = *(const float4*)(y_bw + (size_t)row * D_INNER + i);
    ushort4 uxs = *(const ushort4*)(xbc + (size_t)row * CONV_DIM + i);
    ushort4 uz  = *(const ushort4*)(zx + (size_t)row * D_IN_PROJ + i);
    float dp = Dp[i >> 6];
    float g[4];
    g[0] = (yf.x + yb.x + bf2f(uxs.x) * dp) * siluf(bf2f(uz.x));
    g[1] = (yf.y + yb.y + bf2f(uxs.y) * dp) * siluf(bf2f(uz.y));
    g[2] = (yf.z + yb.z + bf2f(uxs.z) * dp) * siluf(bf2f(uz.z));
    g[3] = (yf.w + yb.w + bf2f(uxs.w) * dp) * siluf(bf2f(uz.w));
    float ss = g[0]*g[0] + g[1]*g[1] + g[2]*g[2] + g[3]*g[3];
#pragma unroll
    for (int m = 1; m < 64; m <<= 1) ss += __shfl_xor(ss, m, 64);
    __shared__ float red[4];
    if ((threadIdx.x & 63) == 0) red[threadIdx.x >> 6] = ss;
    __syncthreads();
    ss = red[0] + red[1] + red[2] + red[3];
    float scale = rsqrtf(ss * (1.f / D_INNER) + EPS);
    float4 rw = *(const float4*)(rms_w + i);
    ushort4 o;
    o.x = f2bf(g[0] * scale * rw.x); o.y = f2bf(g[1] * scale * rw.y);
    o.z = f2bf(g[2] * scale * rw.z); o.w = f2bf(g[3] * scale * rw.w);
    *(ushort4*)(yg + (size_t)row * D_INNER + i) = o;
}

// ---------------- launch ----------------
extern "C" void kernel_launch(void* const* d_in, const int* in_sizes, int n_in,
                              void* d_out, int out_size, void* d_ws, size_t ws_size,
                              hipStream_t stream)
{
    const float* x         = (const float*)d_in[0];
    const float* ln1_w     = (const float*)d_in[1];
    const float* ln1_b     = (const float*)d_in[2];
    const float* in_proj_w = (const float*)d_in[3];
    const float* conv_w    = (const float*)d_in[4];
    const float* conv_b    = (const float*)d_in[5];
    const float* dt_bias   = (const float*)d_in[6];
    const float* A_log     = (const float*)d_in[7];
    const float* Dp        = (const float*)d_in[8];
    const float* rms_w     = (const float*)d_in[9];
    const float* out_proj_w= (const float*)d_in[10];
    const float* ln2_w     = (const float*)d_in[11];
    const float* ln2_b     = (const float*)d_in[12];
    const float* fc1_w     = (const float*)d_in[13];
    const float* fc1_b     = (const float*)d_in[14];
    const float* fc2_w     = (const float*)d_in[15];
    const float* fc2_b     = (const float*)d_in[16];
    float* out = (float*)d_out;

    float* ws0 = (float*)d_ws;
    unsigned short* zx_bf  = (unsigned short*)ws0;
    unsigned short* xbc_bf = (unsigned short*)(ws0 + OFF_XBCB);
    unsigned short* xT_bf  = (unsigned short*)(ws0 + OFF_XT);
    float* y_fw = ws0 + OFF_YFW;
    float* y_bw = ws0 + OFF_YBW;
    float* sreg = ws0 + OFF_SREG;
    unsigned short* sreg16 = (unsigned short*)sreg;
    unsigned short* hA_bf = (unsigned short*)sreg;
    unsigned short* P     = (unsigned short*)(sreg + 2097152);
    unsigned short* yg_bf = (unsigned short*)(sreg + 2686976);
    float* x_res          = sreg + 6881280;
    unsigned short* f1_bf = (unsigned short*)ws0;
    float* cum_tab = out;
    float* dtv_tab = out + 262144;
    float* dtf     = out + 524288;

    // 1. LN1 -> bf16
    ln_kernel<<<dim3(NTOK / 4), dim3(256), 0, stream>>>(x, ln1_w, ln1_b, hA_bf, NTOK);
    // 2. in_proj -> bf16 zx (+ fp32 dt sidecar); grid x = m-tiles
    wconv_kernel<<<dim3(2304 * 512 / 1024), dim3(256), 0, stream>>>(in_proj_w, P, 2208 * 512, 2304 * 512);
    gemm_bf16<<<dim3(64, 18), dim3(256), 0, stream>>>(hA_bf, P, 512, 2208, nullptr, zx_bf, nullptr, nullptr, 0, dtf);
    // 3. conv
    conv_kernel<<<dim3(NTOK * CONV_DIM / 256), dim3(256), 0, stream>>>(zx_bf, conv_w, conv_b, xbc_bf);
    // 4. transpose
    xpose_kernel<<<dim3(32, 16, 4), dim3(256), 0, stream>>>(xbc_bf, xT_bf);
    // 5. tables + boundary zero
    dt_table_kernel<<<dim3(1024), dim3(256), 0, stream>>>(dtf, dt_bias, A_log, cum_tab, dtv_tab);
    bzero_kernel<<<dim3(8), dim3(256), 0, stream>>>(y_fw, y_bw);
    // 6. SSD
    ssd_intra_mfma<<<dim3(1024), dim3(256), 0, stream>>>(xbc_bf, xT_bf, cum_tab, dtv_tab, y_fw, y_bw);
    ssd_state_kernel<<<dim3(4096), dim3(256), 0, stream>>>(xbc_bf, cum_tab, dtv_tab, sreg16);
    ssd_chunkscan_kernel<<<dim3(512), dim3(256), 0, stream>>>(cum_tab, sreg16);
    ssd_inter_mfma<<<dim3(4096), dim3(256), 0, stream>>>(xbc_bf, cum_tab, sreg16, y_fw, y_bw);
    // 7. combine -> bf16 yg
    combine_kernel<<<dim3(NTOK), dim3(256), 0, stream>>>(zx_bf, xbc_bf, y_fw, y_bw, Dp, rms_w, yg_bf);
    // 8. out_proj + residual(x) -> x_res  (64x64 tiles, 4 blocks/CU)
    wconv_kernel<<<dim3(512 * 1024 / 1024), dim3(256), 0, stream>>>(out_proj_w, P, 512 * 1024, 512 * 1024);
    gemm_bf16_t64<<<dim3(128, 8), dim3(256), 0, stream>>>(yg_bf, P, 1024, 512, x_res, nullptr, x);
    // 9. LN2 -> bf16
    ln_kernel<<<dim3(NTOK / 4), dim3(256), 0, stream>>>(x_res, ln2_w, ln2_b, hA_bf, NTOK);
    // 10. fc1 + bias + GELU -> bf16; grid x = m-tiles
    wconv_kernel<<<dim3(2048 * 512 / 1024), dim3(256), 0, stream>>>(fc1_w, P, 2048 * 512, 2048 * 512);
    gemm_bf16<<<dim3(64, 16), dim3(256), 0, stream>>>(hA_bf, P, 512, 2048, nullptr, f1_bf, fc1_b, nullptr, 1, nullptr);
    // 11. fc2 + bias + residual(x_res) -> out  (64x64 tiles)
    wconv_kernel<<<dim3(512 * 2048 / 1024), dim3(256), 0, stream>>>(fc2_w, P, 512 * 2048, 512 * 2048);
    gemm_bf16_t64<<<dim3(128, 8), dim3(256), 0, stream>>>(f1_bf, P, 2048, 512, out, fc2_b, x_res);
}

// Round 9
// 414.643 us; speedup vs baseline: 1.2905x; 1.0999x over previous
//
#include <hip/hip_runtime.h>
#include <math.h>

#define D_MODEL   512
#define D_INNER   1024
#define NHEADS    16
#define HEADDIM   64
#define D_STATE   64
#define D_CONV    7
#define D_FF      2048
#define CONV_DIM  1152
#define D_IN_PROJ 2208
#define BATCH     4
#define SEQLEN    2048
#define NTOK      (BATCH*SEQLEN)
#define EPS       1e-5f

// ---- workspace layout (float32 units) ----
// zx_bf, xbc_bf, xT_bf, y_fw, y_bw as before; sreg overlays:
//   S-tiles (scan):   sreg[0 .. 8388608) floats (bf16 4096x4096sh)
//   hA_bf [0..2097152) | yg_bf [2686976..6881280) | x_res [6881280..11075584)
//   weight pads (converted ONCE at start, disjoint from everything):
//   P_in  sh[22151168..23330816)  P_out sh[23330816..23855104)
//   P_f1  sh[23855104..24903680)  P_f2  sh[24903680..25952256)   (sh = shorts from sreg)
#define OFF_XBCB  9043968ull
#define OFF_XT    13762560ull
#define OFF_YFW   17956864ull
#define OFF_YBW   26345472ull
#define OFF_SREG  34734080ull

typedef __bf16 bf16x8 __attribute__((ext_vector_type(8)));
typedef float  f32x4  __attribute__((ext_vector_type(4)));

__device__ __forceinline__ float siluf(float x) { return x / (1.f + expf(-x)); }
__device__ __forceinline__ float geluf(float x) { return 0.5f * x * (1.f + erff(x * 0.70710678118654752f)); }
__device__ __forceinline__ float softplusf(float x) { return fmaxf(x, 0.f) + log1pf(expf(-fabsf(x))); }
__device__ __forceinline__ int tglob(int d, int c, int t) { int s = c * 64 + t; return d ? (SEQLEN - 1 - s) : s; }
__device__ __forceinline__ unsigned short f2bf(float f) {
    unsigned int u = __float_as_uint(f);
    u += 0x7FFFu + ((u >> 16) & 1u);
    return (unsigned short)(u >> 16);
}
__device__ __forceinline__ float bf2f(unsigned short u) { return __uint_as_float((unsigned)u << 16); }
__device__ __forceinline__ void glds16(const void* g, void* l) {
    __builtin_amdgcn_global_load_lds((const __attribute__((address_space(1))) void*)g,
                                     (__attribute__((address_space(3))) void*)l, 16, 0, 0);
}

// ---------------- LayerNorm -> bf16 ----------------
__global__ __launch_bounds__(256) void ln_kernel(const float* __restrict__ x,
                                                 const float* __restrict__ w,
                                                 const float* __restrict__ b,
                                                 unsigned short* __restrict__ out, int nrows)
{
    int wid = threadIdx.x >> 6;
    int lane = threadIdx.x & 63;
    int row = blockIdx.x * 4 + wid;
    if (row >= nrows) return;
    const float* xr = x + (size_t)row * D_MODEL;
    float4 v0 = *(const float4*)(xr + lane * 8);
    float4 v1 = *(const float4*)(xr + lane * 8 + 4);
    float v[8] = {v0.x, v0.y, v0.z, v0.w, v1.x, v1.y, v1.z, v1.w};
    float s = 0.f;
#pragma unroll
    for (int i = 0; i < 8; i++) s += v[i];
#pragma unroll
    for (int m = 1; m < 64; m <<= 1) s += __shfl_xor(s, m, 64);
    float mu = s * (1.f / D_MODEL);
    float q = 0.f;
#pragma unroll
    for (int i = 0; i < 8; i++) { float dd = v[i] - mu; q += dd * dd; }
#pragma unroll
    for (int m = 1; m < 64; m <<= 1) q += __shfl_xor(q, m, 64);
    float inv = rsqrtf(q * (1.f / D_MODEL) + EPS);
    float4 w0 = *(const float4*)(w + lane * 8);
    float4 w1 = *(const float4*)(w + lane * 8 + 4);
    float4 b0 = *(const float4*)(b + lane * 8);
    float4 b1 = *(const float4*)(b + lane * 8 + 4);
    float o[8];
    o[0] = (v[0]-mu)*inv*w0.x + b0.x; o[1] = (v[1]-mu)*inv*w0.y + b0.y;
    o[2] = (v[2]-mu)*inv*w0.z + b0.z; o[3] = (v[3]-mu)*inv*w0.w + b0.w;
    o[4] = (v[4]-mu)*inv*w1.x + b1.x; o[5] = (v[5]-mu)*inv*w1.y + b1.y;
    o[6] = (v[6]-mu)*inv*w1.z + b1.z; o[7] = (v[7]-mu)*inv*w1.w + b1.w;
    unsigned short* orow = out + (size_t)row * D_MODEL + lane * 8;
    ushort4 p0, p1;
    p0.x = f2bf(o[0]); p0.y = f2bf(o[1]); p0.z = f2bf(o[2]); p0.w = f2bf(o[3]);
    p1.x = f2bf(o[4]); p1.y = f2bf(o[5]); p1.z = f2bf(o[6]); p1.w = f2bf(o[7]);
    *(ushort4*)orow = p0;
    *(ushort4*)(orow + 4) = p1;
}

// ---------------- weight fp32 -> bf16 (zero-pad to dst_n) ----------------
__global__ __launch_bounds__(256) void wconv_kernel(const float* __restrict__ src,
                                                    unsigned short* __restrict__ dst,
                                                    int src_n, int dst_n)
{
    int i = (blockIdx.x * 256 + threadIdx.x) * 4;
    if (i >= dst_n) return;
    ushort4 o;
    if (i < src_n) {
        float4 v = *(const float4*)(src + i);
        o.x = f2bf(v.x); o.y = f2bf(v.y); o.z = f2bf(v.z); o.w = f2bf(v.w);
    } else {
        o.x = o.y = o.z = o.w = 0;
    }
    *(ushort4*)(dst + i) = o;
}

// ---------------- bf16 MFMA GEMM (m97 structure; grid x = m-tile for XCD L2 sharing) ----------------
__global__ __launch_bounds__(256, 2) void gemm_bf16(const unsigned short* __restrict__ A,
                                                    const unsigned short* __restrict__ W,
                                                    int K, int Nreal,
                                                    float* __restrict__ Cf,
                                                    unsigned short* __restrict__ Cb,
                                                    const float* __restrict__ bias,
                                                    const float* __restrict__ res, int act,
                                                    float* __restrict__ dtf)
{
    __shared__ unsigned short As[128 * 32];
    __shared__ unsigned short Ws[128 * 32];
    const int tid = threadIdx.x;
    const int wave = tid >> 6;
    const int lane = tid & 63;
    const int m0 = blockIdx.x * 128;
    const int n0 = blockIdx.y * 128;
    const int wm = (wave & 1) * 64;
    const int wn = (wave >> 1) * 64;

    const size_t gA = (size_t)(m0 + 32 * wave + (lane >> 2)) * K + (lane & 3) * 8;
    const size_t gW = (size_t)(n0 + 32 * wave + (lane >> 2)) * K + (lane & 3) * 8;
    unsigned short* lA = As + wave * 1024 + lane * 8;
    unsigned short* lW = Ws + wave * 1024 + lane * 8;

    const int fr = lane & 15;
    const int fq = (lane >> 4) * 8;
    f32x4 acc[4][4] = {};

    for (int k0 = 0; k0 < K; k0 += 32) {
        glds16(A + gA + k0, lA);
        glds16(A + gA + (size_t)16 * K + k0, lA + 512);
        glds16(W + gW + k0, lW);
        glds16(W + gW + (size_t)16 * K + k0, lW + 512);
        __syncthreads();
        bf16x8 af[4], bf[4];
#pragma unroll
        for (int mi = 0; mi < 4; mi++)
            af[mi] = *(const bf16x8*)(As + (wm + mi * 16 + fr) * 32 + fq);
#pragma unroll
        for (int ni = 0; ni < 4; ni++)
            bf[ni] = *(const bf16x8*)(Ws + (wn + ni * 16 + fr) * 32 + fq);
#pragma unroll
        for (int mi = 0; mi < 4; mi++)
#pragma unroll
            for (int ni = 0; ni < 4; ni++)
                acc[mi][ni] = __builtin_amdgcn_mfma_f32_16x16x32_bf16(af[mi], bf[ni], acc[mi][ni], 0, 0, 0);
        __syncthreads();
    }

    const int colb = n0 + wn + (lane & 15);
    const int rowb = m0 + wm + (lane >> 4) * 4;
#pragma unroll
    for (int mi = 0; mi < 4; mi++) {
#pragma unroll
        for (int ni = 0; ni < 4; ni++) {
            int col = colb + ni * 16;
            if (col < Nreal) {
#pragma unroll
                for (int r = 0; r < 4; r++) {
                    int row = rowb + mi * 16 + r;
                    float v = acc[mi][ni][r];
                    size_t idx = (size_t)row * Nreal + col;
                    if (bias) v += bias[col];
                    if (res) v += res[idx];
                    if (act) v = geluf(v);
                    if (Cb) {
                        Cb[idx] = f2bf(v);
                        if (dtf && col >= 2176) dtf[(size_t)row * 32 + (col - 2176)] = v;
                    } else Cf[idx] = v;
                }
            }
        }
    }
}

// ---------------- 64x64-tile bf16 MFMA GEMM for skinny-N tails ----------------
__global__ __launch_bounds__(256) void gemm_bf16_t64(const unsigned short* __restrict__ A,
                                                     const unsigned short* __restrict__ W,
                                                     int K, int N,
                                                     float* __restrict__ Cf,
                                                     const float* __restrict__ bias,
                                                     const float* __restrict__ res)
{
    __shared__ unsigned short As[64 * 32];
    __shared__ unsigned short Ws[64 * 32];
    const int tid = threadIdx.x;
    const int wave = tid >> 6;
    const int lane = tid & 63;
    const int m0 = blockIdx.x * 64;
    const int n0 = blockIdx.y * 64;

    const size_t gA = (size_t)(m0 + (tid >> 2)) * K + (tid & 3) * 8;
    const size_t gW = (size_t)(n0 + (tid >> 2)) * K + (tid & 3) * 8;
    unsigned short* lA = As + tid * 8;
    unsigned short* lW = Ws + tid * 8;

    const int fr = lane & 15;
    const int fq = (lane >> 4) * 8;
    f32x4 acc[4] = {};

    for (int k0 = 0; k0 < K; k0 += 32) {
        glds16(A + gA + k0, lA);
        glds16(W + gW + k0, lW);
        __syncthreads();
        bf16x8 af = *(const bf16x8*)(As + (wave * 16 + fr) * 32 + fq);
#pragma unroll
        for (int ni = 0; ni < 4; ni++) {
            bf16x8 bfr = *(const bf16x8*)(Ws + (ni * 16 + fr) * 32 + fq);
            acc[ni] = __builtin_amdgcn_mfma_f32_16x16x32_bf16(af, bfr, acc[ni], 0, 0, 0);
        }
        __syncthreads();
    }

    const int col0 = n0 + (lane & 15);
    const int rowb = m0 + wave * 16 + (lane >> 4) * 4;
#pragma unroll
    for (int ni = 0; ni < 4; ni++) {
        int col = col0 + ni * 16;
        float bb = bias ? bias[col] : 0.f;
#pragma unroll
        for (int r = 0; r < 4; r++) {
            int row = rowb + r;
            size_t idx = (size_t)row * N + col;
            float v = acc[ni][r] + bb;
            if (res) v += res[idx];
            Cf[idx] = v;
        }
    }
}

// ---------------- depthwise causal conv: 4 channels x 8 timesteps per thread ----------------
__global__ __launch_bounds__(256) void conv_kernel(const unsigned short* __restrict__ zx,
                                                   const float* __restrict__ conv_w,
                                                   const float* __restrict__ conv_b,
                                                   unsigned short* __restrict__ out)
{
    int gid = blockIdx.x * 256 + threadIdx.x;   // 288 c-quads * 1024 t-tiles
    int c4 = gid % 288;
    int tt = gid / 288;
    int c = c4 * 4;
    int b = tt >> 8;
    int t0 = (tt & 255) * 8;

    float wgt[4][7], bias[4];
#pragma unroll
    for (int q = 0; q < 4; q++) {
        bias[q] = conv_b[c + q];
#pragma unroll
        for (int j = 0; j < 7; j++) wgt[q][j] = conv_w[(c + q) * 7 + j];
    }

    float xin[4][14];
    const unsigned short* base = zx + (size_t)(b * SEQLEN + t0) * D_IN_PROJ + D_INNER + c;
#pragma unroll
    for (int j = 0; j < 14; j++) {
        int t = t0 - 6 + j;
        ushort4 v = make_ushort4(0, 0, 0, 0);
        if (t >= 0) v = *(const ushort4*)(base + (ptrdiff_t)(j - 6) * D_IN_PROJ);
        xin[0][j] = bf2f(v.x); xin[1][j] = bf2f(v.y);
        xin[2][j] = bf2f(v.z); xin[3][j] = bf2f(v.w);
    }

    unsigned short* orow = out + (size_t)(b * SEQLEN + t0) * CONV_DIM + c;
#pragma unroll
    for (int i = 0; i < 8; i++) {
        ushort4 o;
        float a0 = bias[0], a1 = bias[1], a2 = bias[2], a3 = bias[3];
#pragma unroll
        for (int j = 0; j < 7; j++) {
            a0 = fmaf(wgt[0][j], xin[0][i + j], a0);
            a1 = fmaf(wgt[1][j], xin[1][i + j], a1);
            a2 = fmaf(wgt[2][j], xin[2][i + j], a2);
            a3 = fmaf(wgt[3][j], xin[3][i + j], a3);
        }
        o.x = f2bf(siluf(a0)); o.y = f2bf(siluf(a1));
        o.z = f2bf(siluf(a2)); o.w = f2bf(siluf(a3));
        *(ushort4*)(orow + (size_t)i * CONV_DIM) = o;
    }
}

// ---------------- transpose xs: xbc_bf[:, :1024] -> xT[b][p][t] ----------------
__global__ __launch_bounds__(256) void xpose_kernel(const unsigned short* __restrict__ xbc,
                                                    unsigned short* __restrict__ xT)
{
    int tt = blockIdx.x, pt = blockIdx.y, b = blockIdx.z;
    __shared__ unsigned short T[64][68];
    {
        int r = threadIdx.x >> 4, q = threadIdx.x & 15;
#pragma unroll
        for (int i = 0; i < 4; i++) {
            int t = tt * 64 + r + i * 16;
            ushort4 v = *(const ushort4*)(xbc + (size_t)(b * SEQLEN + t) * CONV_DIM + pt * 64 + q * 4);
            *(ushort4*)&T[r + i * 16][q * 4] = v;
        }
    }
    __syncthreads();
    {
        int p = threadIdx.x >> 4, tq = threadIdx.x & 15;
#pragma unroll
        for (int i = 0; i < 4; i++) {
            int pp = p + i * 16;
            ushort4 o;
            o.x = T[tq * 4 + 0][pp]; o.y = T[tq * 4 + 1][pp];
            o.z = T[tq * 4 + 2][pp]; o.w = T[tq * 4 + 3][pp];
            *(ushort4*)(xT + ((size_t)b * 1024 + pt * 64 + pp) * 2048 + tt * 64 + tq * 4) = o;
        }
    }
}

// ---------------- dt/cum tables ----------------
__global__ __launch_bounds__(256) void dt_table_kernel(const float* __restrict__ dtf,
                                                       const float* __restrict__ dt_bias,
                                                       const float* __restrict__ A_log,
                                                       float* __restrict__ cum_tab,
                                                       float* __restrict__ dtv_tab)
{
    int wid = blockIdx.x * 4 + (threadIdx.x >> 6);
    int lane = threadIdx.x & 63;
    int c = wid & 31, h = (wid >> 5) & 15, b = (wid >> 9) & 3, d = wid >> 11;
    int tg = tglob(d, c, lane);
    float raw = dtf[(size_t)(b * SEQLEN + tg) * 32 + d * 16 + h] + dt_bias[h];
    float dtv = softplusf(raw);
    float cum = -expf(A_log[h]) * dtv;
#pragma unroll
    for (int off = 1; off < 64; off <<= 1) {
        int src = lane - off;
        float o = __shfl(cum, src < 0 ? 0 : src, 64);
        if (lane >= off) cum += o;
    }
    cum_tab[(size_t)wid * 64 + lane] = cum;
    dtv_tab[(size_t)wid * 64 + lane] = dtv;
}

// ---------------- zero boundary rows ----------------
__global__ __launch_bounds__(256) void bzero_kernel(float* __restrict__ y_fw, float* __restrict__ y_bw)
{
    int b = blockIdx.x >> 1, d = blockIdx.x & 1;
    float* row = d ? (y_bw + (size_t)(b * SEQLEN + SEQLEN - 1) * D_INNER)
                   : (y_fw + (size_t)(b * SEQLEN) * D_INNER);
    *(float4*)(row + threadIdx.x * 4) = make_float4(0.f, 0.f, 0.f, 0.f);
}

// ---------------- K1: intra-chunk, MFMA ----------------
__global__ __launch_bounds__(256) void ssd_intra_mfma(const unsigned short* __restrict__ xbc,
                                                      const unsigned short* __restrict__ xT,
                                                      const float* __restrict__ cum_tab,
                                                      const float* __restrict__ dtv_tab,
                                                      float* __restrict__ y_fw,
                                                      float* __restrict__ y_bw)
{
    const int bid = blockIdx.x;
    const int hq = bid & 3, c = (bid >> 2) & 31, b = (bid >> 7) & 3, d = bid >> 9;
    const int tid = threadIdx.x, wave = tid >> 6, lane = tid & 63;

    __shared__ unsigned short BnMt[64 * 80];
    __shared__ unsigned short CnXt[64 * 80];
    __shared__ float Gm[64 * 68];
    __shared__ float cum_l[64], dtv_l[64];

    {
        int s = tid >> 2, nq = (tid & 3) * 16;
        int tg = tglob(d, c, s);
        const unsigned short* row = xbc + (size_t)(b * SEQLEN + tg) * CONV_DIM;
#pragma unroll
        for (int k = 0; k < 16; k += 4) {
            *(ushort4*)&BnMt[s * 80 + nq + k] = *(const ushort4*)(row + 1024 + nq + k);
            *(ushort4*)&CnXt[s * 80 + nq + k] = *(const ushort4*)(row + 1088 + nq + k);
        }
    }
    __syncthreads();
    {
        f32x4 ga[4] = {};
        const int mrow = wave * 16 + (lane & 15);
        const int kq = (lane >> 4) * 8;
#pragma unroll
        for (int k0 = 0; k0 < 64; k0 += 32) {
            bf16x8 afr = *(const bf16x8*)&BnMt[mrow * 80 + k0 + kq];
#pragma unroll
            for (int ni = 0; ni < 4; ni++) {
                bf16x8 bfr = *(const bf16x8*)&CnXt[(ni * 16 + (lane & 15)) * 80 + k0 + kq];
                ga[ni] = __builtin_amdgcn_mfma_f32_16x16x32_bf16(afr, bfr, ga[ni], 0, 0, 0);
            }
        }
        int col = lane & 15, quad = lane >> 4;
#pragma unroll
        for (int ni = 0; ni < 4; ni++)
#pragma unroll
            for (int r = 0; r < 4; r++)
                Gm[(wave * 16 + quad * 4 + r) * 68 + ni * 16 + col] = ga[ni][r];
    }

    for (int hh = 0; hh < 4; hh++) {
        const int h = hq * 4 + hh;
        __syncthreads();
        if (tid < 64) {
            int flat = ((d * 4 + b) * 16 + h) * 32 + c;
            cum_l[tid] = cum_tab[(size_t)flat * 64 + tid];
            dtv_l[tid] = dtv_tab[(size_t)flat * 64 + tid];
        }
        {
            const unsigned short* xrow = xT + ((size_t)b * 1024 + h * 64) * 2048;
            int p = tid >> 4, tq = tid & 15;
#pragma unroll
            for (int pi = 0; pi < 4; pi++, p += 16) {
                if (d == 0) {
                    ushort4 v = *(const ushort4*)(xrow + (size_t)p * 2048 + c * 64 + tq * 4);
                    *(ushort4*)&CnXt[p * 80 + tq * 4] = v;
                } else {
                    int base = SEQLEN - 64 - c * 64;
                    ushort4 v = *(const ushort4*)(xrow + (size_t)p * 2048 + base + (15 - tq) * 4);
                    CnXt[p * 80 + tq * 4 + 0] = v.w;
                    CnXt[p * 80 + tq * 4 + 1] = v.z;
                    CnXt[p * 80 + tq * 4 + 2] = v.y;
                    CnXt[p * 80 + tq * 4 + 3] = v.x;
                }
            }
        }
        __syncthreads();
        {
            int s = tid & 63, tq = tid >> 6;
            float cs = cum_l[s], dv = dtv_l[s];
#pragma unroll
            for (int j = 0; j < 16; j++) {
                int t = tq * 16 + j;
                float g = Gm[s * 68 + t];
                float m = (s <= t) ? g * expf(cum_l[t] - cs) * dv : 0.f;
                BnMt[t * 80 + s] = f2bf(m);
            }
        }
        __syncthreads();
        {
            f32x4 acc[4] = {};
            const int mrow = wave * 16 + (lane & 15);
            const int kq = (lane >> 4) * 8;
#pragma unroll
            for (int k0 = 0; k0 < 64; k0 += 32) {
                bf16x8 afr = *(const bf16x8*)&BnMt[mrow * 80 + k0 + kq];
#pragma unroll
                for (int ni = 0; ni < 4; ni++) {
                    bf16x8 bfr = *(const bf16x8*)&CnXt[(ni * 16 + (lane & 15)) * 80 + k0 + kq];
                    acc[ni] = __builtin_amdgcn_mfma_f32_16x16x32_bf16(afr, bfr, acc[ni], 0, 0, 0);
                }
            }
            float* ybuf = d ? y_bw : y_fw;
            int quad = lane >> 4, col0 = lane & 15;
#pragma unroll
            for (int r = 0; r < 4; r++) {
                int tl = wave * 16 + quad * 4 + r;
                int tg = tglob(d, c, tl);
                int tout = d ? (tg - 1) : (tg + 1);
                if (tout >= 0 && tout < SEQLEN) {
                    float* yp = ybuf + (size_t)(b * SEQLEN + tout) * D_INNER + h * 64;
#pragma unroll
                    for (int ni = 0; ni < 4; ni++)
                        yp[ni * 16 + col0] = acc[ni][r];
                }
            }
        }
    }
}

// ---------------- K2: per-chunk state S'[p][n] -> bf16 tiles ----------------
__global__ __launch_bounds__(256) void ssd_state_kernel(const unsigned short* __restrict__ xbc,
                                                        const float* __restrict__ cum_tab,
                                                        const float* __restrict__ dtv_tab,
                                                        unsigned short* __restrict__ sreg16)
{
    const int flat = blockIdx.x;
    const int c = flat & 31, h = (flat >> 5) & 15, b = (flat >> 9) & 3, d = flat >> 11;
    const int tid = threadIdx.x;
    const int ty = tid >> 4, tx = tid & 15;

    __shared__ float Bm[64][64];
    __shared__ float Xw[64][64];
    __shared__ float cum_l[64], dtv_l[64];

    if (tid < 64) {
        cum_l[tid] = cum_tab[(size_t)flat * 64 + tid];
        dtv_l[tid] = dtv_tab[(size_t)flat * 64 + tid];
    }
    __syncthreads();
    float clast = cum_l[63];
    for (int idx = tid; idx < 1024; idx += 256) {
        int s = idx >> 4, q = idx & 15;
        int tg = tglob(d, c, s);
        const unsigned short* row = xbc + (size_t)(b * SEQLEN + tg) * CONV_DIM;
        ushort4 ub = *(const ushort4*)(row + 1024 + q * 4);
        ushort4 ux = *(const ushort4*)(row + h * 64 + q * 4);
        float w = expf(clast - cum_l[s]) * dtv_l[s];
        Bm[s][q*4+0] = bf2f(ub.x); Bm[s][q*4+1] = bf2f(ub.y);
        Bm[s][q*4+2] = bf2f(ub.z); Bm[s][q*4+3] = bf2f(ub.w);
        Xw[s][q*4+0] = bf2f(ux.x)*w; Xw[s][q*4+1] = bf2f(ux.y)*w;
        Xw[s][q*4+2] = bf2f(ux.z)*w; Xw[s][q*4+3] = bf2f(ux.w)*w;
    }
    __syncthreads();
    float acc[4][4] = {};
    for (int s = 0; s < 64; s++) {
        float4 xv = *(const float4*)&Xw[s][ty * 4];
        float4 bv = *(const float4*)&Bm[s][tx * 4];
        float xx[4] = {xv.x, xv.y, xv.z, xv.w};
        float bb[4] = {bv.x, bv.y, bv.z, bv.w};
#pragma unroll
        for (int i = 0; i < 4; i++)
#pragma unroll
            for (int j = 0; j < 4; j++) acc[i][j] = fmaf(xx[i], bb[j], acc[i][j]);
    }
    unsigned short* st = sreg16 + (size_t)flat * 4096;
#pragma unroll
    for (int i = 0; i < 4; i++) {
        ushort4 o;
        o.x = f2bf(acc[i][0]); o.y = f2bf(acc[i][1]);
        o.z = f2bf(acc[i][2]); o.w = f2bf(acc[i][3]);
        *(ushort4*)&st[(size_t)(ty * 4 + i) * 64 + tx * 4] = o;
    }
}

// ---------------- K3: serial chunk scan ----------------
__global__ __launch_bounds__(256) void ssd_chunkscan_kernel(const float* __restrict__ cum_tab,
                                                            unsigned short* __restrict__ sreg16)
{
    const int ps = blockIdx.x & 3;
    const int g  = blockIdx.x >> 2;
    const int tid = threadIdx.x;
    const int base = g * 32;
    const size_t off = (size_t)ps * 1024 + tid * 4;
    float h0 = 0.f, h1 = 0.f, h2 = 0.f, h3 = 0.f;
    ushort4 s = *(ushort4*)(sreg16 + (size_t)base * 4096 + off);
    for (int c = 0; c < 32; c++) {
        int flat = base + c;
        ushort4 snext;
        if (c < 31) snext = *(ushort4*)(sreg16 + (size_t)(flat + 1) * 4096 + off);
        float dec = expf(cum_tab[(size_t)flat * 64 + 63]);
        ushort4 o;
        o.x = f2bf(h0); o.y = f2bf(h1); o.z = f2bf(h2); o.w = f2bf(h3);
        *(ushort4*)(sreg16 + (size_t)flat * 4096 + off) = o;
        h0 = h0 * dec + bf2f(s.x);
        h1 = h1 * dec + bf2f(s.y);
        h2 = h2 * dec + bf2f(s.z);
        h3 = h3 * dec + bf2f(s.w);
        s = snext;
    }
}

// ---------------- K4: inter-chunk, MFMA ----------------
__global__ __launch_bounds__(256) void ssd_inter_mfma(const unsigned short* __restrict__ xbc,
                                                      const float* __restrict__ cum_tab,
                                                      const unsigned short* __restrict__ sreg16,
                                                      float* __restrict__ y_fw,
                                                      float* __restrict__ y_bw)
{
    const int flat = blockIdx.x;
    const int c = flat & 31;
    if (c == 0) return;
    const int h = (flat >> 5) & 15, b = (flat >> 9) & 3, d = flat >> 11;
    const int tid = threadIdx.x, wave = tid >> 6, lane = tid & 63;

    __shared__ unsigned short Cs[64 * 72];
    __shared__ unsigned short Hs[64 * 72];
    __shared__ float cum_l[64];

    if (tid < 64) cum_l[tid] = cum_tab[(size_t)flat * 64 + tid];
    {
        int s = tid >> 2, nq = (tid & 3) * 16;
        int tg = tglob(d, c, s);
        const unsigned short* row = xbc + (size_t)(b * SEQLEN + tg) * CONV_DIM + 1088;
        const unsigned short* st = sreg16 + (size_t)flat * 4096 + s * 64;
#pragma unroll
        for (int k = 0; k < 16; k += 4) {
            *(ushort4*)&Cs[s * 72 + nq + k] = *(const ushort4*)(row + nq + k);
            *(ushort4*)&Hs[s * 72 + nq + k] = *(const ushort4*)(st + nq + k);
        }
    }
    __syncthreads();
    f32x4 acc[4] = {};
    const int fr = lane & 15, kq = (lane >> 4) * 8;
    const int mrow = wave * 16 + fr;
#pragma unroll
    for (int k0 = 0; k0 < 64; k0 += 32) {
        bf16x8 afr = *(const bf16x8*)&Cs[mrow * 72 + k0 + kq];
#pragma unroll
        for (int ni = 0; ni < 4; ni++) {
            bf16x8 bfr = *(const bf16x8*)&Hs[(ni * 16 + fr) * 72 + k0 + kq];
            acc[ni] = __builtin_amdgcn_mfma_f32_16x16x32_bf16(afr, bfr, acc[ni], 0, 0, 0);
        }
    }
    float* ybuf = d ? y_bw : y_fw;
    int quad = lane >> 4, col0 = lane & 15;
#pragma unroll
    for (int r = 0; r < 4; r++) {
        int tl = wave * 16 + quad * 4 + r;
        float a = expf(cum_l[tl]);
        int tg = tglob(d, c, tl);
        int tout = d ? (tg - 1) : (tg + 1);
        if (tout >= 0 && tout < SEQLEN) {
            float* yp = ybuf + (size_t)(b * SEQLEN + tout) * D_INNER + h * 64;
#pragma unroll
            for (int ni = 0; ni < 4; ni++)
                yp[ni * 16 + col0] += acc[ni][r] * a;
        }
    }
}

// ---------------- combine -> bf16 yg ----------------
__global__ __launch_bounds__(256) void combine_kernel(const unsigned short* __restrict__ zx,
                                                      const unsigned short* __restrict__ xbc,
                                                      const float* __restrict__ y_fw,
                                                      const float* __restrict__ y_bw,
                                                      const float* __restrict__ Dp,
                                                      const float* __restrict__ rms_w,
                                                      unsigned short* __restrict__ yg)
{
    int row = blockIdx.x;
    int i = threadIdx.x * 4;
    float4 yf = *(const float4*)(y_fw + (size_t)row * D_INNER + i);
    float4 yb = *(const float4*)(y_bw + (size_t)row * D_INNER + i);
    ushort4 uxs = *(const ushort4*)(xbc + (size_t)row * CONV_DIM + i);
    ushort4 uz  = *(const ushort4*)(zx + (size_t)row * D_IN_PROJ + i);
    float dp = Dp[i >> 6];
    float g[4];
    g[0] = (yf.x + yb.x + bf2f(uxs.x) * dp) * siluf(bf2f(uz.x));
    g[1] = (yf.y + yb.y + bf2f(uxs.y) * dp) * siluf(bf2f(uz.y));
    g[2] = (yf.z + yb.z + bf2f(uxs.z) * dp) * siluf(bf2f(uz.z));
    g[3] = (yf.w + yb.w + bf2f(uxs.w) * dp) * siluf(bf2f(uz.w));
    float ss = g[0]*g[0] + g[1]*g[1] + g[2]*g[2] + g[3]*g[3];
#pragma unroll
    for (int m = 1; m < 64; m <<= 1) ss += __shfl_xor(ss, m, 64);
    __shared__ float red[4];
    if ((threadIdx.x & 63) == 0) red[threadIdx.x >> 6] = ss;
    __syncthreads();
    ss = red[0] + red[1] + red[2] + red[3];
    float scale = rsqrtf(ss * (1.f / D_INNER) + EPS);
    float4 rw = *(const float4*)(rms_w + i);
    ushort4 o;
    o.x = f2bf(g[0] * scale * rw.x); o.y = f2bf(g[1] * scale * rw.y);
    o.z = f2bf(g[2] * scale * rw.z); o.w = f2bf(g[3] * scale * rw.w);
    *(ushort4*)(yg + (size_t)row * D_INNER + i) = o;
}

// ---------------- launch ----------------
extern "C" void kernel_launch(void* const* d_in, const int* in_sizes, int n_in,
                              void* d_out, int out_size, void* d_ws, size_t ws_size,
                              hipStream_t stream)
{
    const float* x         = (const float*)d_in[0];
    const float* ln1_w     = (const float*)d_in[1];
    const float* ln1_b     = (const float*)d_in[2];
    const float* in_proj_w = (const float*)d_in[3];
    const float* conv_w    = (const float*)d_in[4];
    const float* conv_b    = (const float*)d_in[5];
    const float* dt_bias   = (const float*)d_in[6];
    const float* A_log     = (const float*)d_in[7];
    const float* Dp        = (const float*)d_in[8];
    const float* rms_w     = (const float*)d_in[9];
    const float* out_proj_w= (const float*)d_in[10];
    const float* ln2_w     = (const float*)d_in[11];
    const float* ln2_b     = (const float*)d_in[12];
    const float* fc1_w     = (const float*)d_in[13];
    const float* fc1_b     = (const float*)d_in[14];
    const float* fc2_w     = (const float*)d_in[15];
    const float* fc2_b     = (const float*)d_in[16];
    float* out = (float*)d_out;

    float* ws0 = (float*)d_ws;
    unsigned short* zx_bf  = (unsigned short*)ws0;
    unsigned short* xbc_bf = (unsigned short*)(ws0 + OFF_XBCB);
    unsigned short* xT_bf  = (unsigned short*)(ws0 + OFF_XT);
    float* y_fw = ws0 + OFF_YFW;
    float* y_bw = ws0 + OFF_YBW;
    float* sreg = ws0 + OFF_SREG;
    unsigned short* sreg16 = (unsigned short*)sreg;
    unsigned short* hA_bf = (unsigned short*)sreg;
    unsigned short* yg_bf = (unsigned short*)(sreg + 2686976);
    float* x_res          = sreg + 6881280;
    unsigned short* sh    = (unsigned short*)sreg;          // short-indexed view of sreg
    unsigned short* P_in  = sh + 22151168;                  // above x_res, disjoint from S-tiles
    unsigned short* P_out = sh + 23330816;
    unsigned short* P_f1  = sh + 23855104;
    unsigned short* P_f2  = sh + 24903680;
    unsigned short* f1_bf = (unsigned short*)ws0;
    float* cum_tab = out;
    float* dtv_tab = out + 262144;
    float* dtf     = out + 524288;

    // 0. all weight conversions up-front (disjoint pads, no inter-GEMM stalls)
    wconv_kernel<<<dim3(2304 * 512 / 1024), dim3(256), 0, stream>>>(in_proj_w, P_in, 2208 * 512, 2304 * 512);
    wconv_kernel<<<dim3(512 * 1024 / 1024), dim3(256), 0, stream>>>(out_proj_w, P_out, 512 * 1024, 512 * 1024);
    wconv_kernel<<<dim3(2048 * 512 / 1024), dim3(256), 0, stream>>>(fc1_w, P_f1, 2048 * 512, 2048 * 512);
    wconv_kernel<<<dim3(512 * 2048 / 1024), dim3(256), 0, stream>>>(fc2_w, P_f2, 512 * 2048, 512 * 2048);
    // 1. LN1 -> bf16
    ln_kernel<<<dim3(NTOK / 4), dim3(256), 0, stream>>>(x, ln1_w, ln1_b, hA_bf, NTOK);
    // 2. in_proj -> bf16 zx (+ fp32 dt sidecar)
    gemm_bf16<<<dim3(64, 18), dim3(256), 0, stream>>>(hA_bf, P_in, 512, 2208, nullptr, zx_bf, nullptr, nullptr, 0, dtf);
    // 3. conv (register-tiled 4c x 8t)
    conv_kernel<<<dim3(288 * 1024 / 256), dim3(256), 0, stream>>>(zx_bf, conv_w, conv_b, xbc_bf);
    // 4. transpose
    xpose_kernel<<<dim3(32, 16, 4), dim3(256), 0, stream>>>(xbc_bf, xT_bf);
    // 5. tables + boundary zero
    dt_table_kernel<<<dim3(1024), dim3(256), 0, stream>>>(dtf, dt_bias, A_log, cum_tab, dtv_tab);
    bzero_kernel<<<dim3(8), dim3(256), 0, stream>>>(y_fw, y_bw);
    // 6. SSD
    ssd_intra_mfma<<<dim3(1024), dim3(256), 0, stream>>>(xbc_bf, xT_bf, cum_tab, dtv_tab, y_fw, y_bw);
    ssd_state_kernel<<<dim3(4096), dim3(256), 0, stream>>>(xbc_bf, cum_tab, dtv_tab, sreg16);
    ssd_chunkscan_kernel<<<dim3(512), dim3(256), 0, stream>>>(cum_tab, sreg16);
    ssd_inter_mfma<<<dim3(4096), dim3(256), 0, stream>>>(xbc_bf, cum_tab, sreg16, y_fw, y_bw);
    // 7. combine -> bf16 yg
    combine_kernel<<<dim3(NTOK), dim3(256), 0, stream>>>(zx_bf, xbc_bf, y_fw, y_bw, Dp, rms_w, yg_bf);
    // 8. out_proj + residual(x) -> x_res
    gemm_bf16_t64<<<dim3(128, 8), dim3(256), 0, stream>>>(yg_bf, P_out, 1024, 512, x_res, nullptr, x);
    // 9. LN2 -> bf16
    ln_kernel<<<dim3(NTOK / 4), dim3(256), 0, stream>>>(x_res, ln2_w, ln2_b, hA_bf, NTOK);
    // 10. fc1 + bias + GELU -> bf16
    gemm_bf16<<<dim3(64, 16), dim3(256), 0, stream>>>(hA_bf, P_f1, 512, 2048, nullptr, f1_bf, fc1_b, nullptr, 1, nullptr);
    // 11. fc2 + bias + residual(x_res) -> out
    gemm_bf16_t64<<<dim3(128, 8), dim3(256), 0, stream>>>(f1_bf, P_f2, 2048, 512, out, fc2_b, x_res);
}

// Round 10
// 397.583 us; speedup vs baseline: 1.3459x; 1.0429x over previous
//
#include <hip/hip_runtime.h>
#include <math.h>

#define D_MODEL   512
#define D_INNER   1024
#define NHEADS    16
#define HEADDIM   64
#define D_STATE   64
#define D_CONV    7
#define D_FF      2048
#define CONV_DIM  1152
#define D_IN_PROJ 2208
#define BATCH     4
#define SEQLEN    2048
#define NTOK      (BATCH*SEQLEN)
#define EPS       1e-5f

// ---- workspace layout (float32 units) ----  (see R5/R6/R9 journal)
#define OFF_XBCB  9043968ull
#define OFF_XT    13762560ull
#define OFF_YFW   17956864ull
#define OFF_YBW   26345472ull
#define OFF_SREG  34734080ull

typedef __bf16 bf16x8 __attribute__((ext_vector_type(8)));
typedef float  f32x4  __attribute__((ext_vector_type(4)));

__device__ __forceinline__ float siluf(float x) { return x / (1.f + expf(-x)); }
__device__ __forceinline__ float geluf(float x) { return 0.5f * x * (1.f + erff(x * 0.70710678118654752f)); }
__device__ __forceinline__ float softplusf(float x) { return fmaxf(x, 0.f) + log1pf(expf(-fabsf(x))); }
__device__ __forceinline__ int tglob(int d, int c, int t) { int s = c * 64 + t; return d ? (SEQLEN - 1 - s) : s; }
__device__ __forceinline__ unsigned short f2bf(float f) {
    unsigned int u = __float_as_uint(f);
    u += 0x7FFFu + ((u >> 16) & 1u);
    return (unsigned short)(u >> 16);
}
__device__ __forceinline__ float bf2f(unsigned short u) { return __uint_as_float((unsigned)u << 16); }
__device__ __forceinline__ void glds16(const void* g, void* l) {
    __builtin_amdgcn_global_load_lds((const __attribute__((address_space(1))) void*)g,
                                     (__attribute__((address_space(3))) void*)l, 16, 0, 0);
}

// ---------------- LayerNorm -> bf16 ----------------
__global__ __launch_bounds__(256) void ln_kernel(const float* __restrict__ x,
                                                 const float* __restrict__ w,
                                                 const float* __restrict__ b,
                                                 unsigned short* __restrict__ out, int nrows)
{
    int wid = threadIdx.x >> 6;
    int lane = threadIdx.x & 63;
    int row = blockIdx.x * 4 + wid;
    if (row >= nrows) return;
    const float* xr = x + (size_t)row * D_MODEL;
    float4 v0 = *(const float4*)(xr + lane * 8);
    float4 v1 = *(const float4*)(xr + lane * 8 + 4);
    float v[8] = {v0.x, v0.y, v0.z, v0.w, v1.x, v1.y, v1.z, v1.w};
    float s = 0.f;
#pragma unroll
    for (int i = 0; i < 8; i++) s += v[i];
#pragma unroll
    for (int m = 1; m < 64; m <<= 1) s += __shfl_xor(s, m, 64);
    float mu = s * (1.f / D_MODEL);
    float q = 0.f;
#pragma unroll
    for (int i = 0; i < 8; i++) { float dd = v[i] - mu; q += dd * dd; }
#pragma unroll
    for (int m = 1; m < 64; m <<= 1) q += __shfl_xor(q, m, 64);
    float inv = rsqrtf(q * (1.f / D_MODEL) + EPS);
    float4 w0 = *(const float4*)(w + lane * 8);
    float4 w1 = *(const float4*)(w + lane * 8 + 4);
    float4 b0 = *(const float4*)(b + lane * 8);
    float4 b1 = *(const float4*)(b + lane * 8 + 4);
    float o[8];
    o[0] = (v[0]-mu)*inv*w0.x + b0.x; o[1] = (v[1]-mu)*inv*w0.y + b0.y;
    o[2] = (v[2]-mu)*inv*w0.z + b0.z; o[3] = (v[3]-mu)*inv*w0.w + b0.w;
    o[4] = (v[4]-mu)*inv*w1.x + b1.x; o[5] = (v[5]-mu)*inv*w1.y + b1.y;
    o[6] = (v[6]-mu)*inv*w1.z + b1.z; o[7] = (v[7]-mu)*inv*w1.w + b1.w;
    unsigned short* orow = out + (size_t)row * D_MODEL + lane * 8;
    ushort4 p0, p1;
    p0.x = f2bf(o[0]); p0.y = f2bf(o[1]); p0.z = f2bf(o[2]); p0.w = f2bf(o[3]);
    p1.x = f2bf(o[4]); p1.y = f2bf(o[5]); p1.z = f2bf(o[6]); p1.w = f2bf(o[7]);
    *(ushort4*)orow = p0;
    *(ushort4*)(orow + 4) = p1;
}

// ---------------- all weight fp32 -> bf16 pads, one launch ----------------
// vec4 ranges: in_proj 294912 (src 282624), out_proj 131072, fc1 262144, fc2 262144
__global__ __launch_bounds__(256) void wconv_all(const float* __restrict__ w0, unsigned short* __restrict__ p0,
                                                 const float* __restrict__ w1, unsigned short* __restrict__ p1,
                                                 const float* __restrict__ w2, unsigned short* __restrict__ p2,
                                                 const float* __restrict__ w3, unsigned short* __restrict__ p3)
{
    int i = blockIdx.x * 256 + threadIdx.x;
    const float* src; unsigned short* dst; int srcn;
    if (i < 294912)      { src = w0; dst = p0; srcn = 282624; }
    else if (i < 425984) { i -= 294912; src = w1; dst = p1; srcn = 131072; }
    else if (i < 688128) { i -= 425984; src = w2; dst = p2; srcn = 262144; }
    else                 { i -= 688128; src = w3; dst = p3; srcn = 262144; }
    ushort4 o = make_ushort4(0, 0, 0, 0);
    if (i < srcn) {
        float4 v = ((const float4*)src)[i];
        o.x = f2bf(v.x); o.y = f2bf(v.y); o.z = f2bf(v.z); o.w = f2bf(v.w);
    }
    ((ushort4*)dst)[i] = o;
}

// ---------------- bf16 MFMA GEMM: BK=64 twin-buffer (half the barriers) ----------------
__global__ __launch_bounds__(256, 2) void gemm_bf16(const unsigned short* __restrict__ A,
                                                    const unsigned short* __restrict__ W,
                                                    int K, int Nreal,
                                                    float* __restrict__ Cf,
                                                    unsigned short* __restrict__ Cb,
                                                    const float* __restrict__ bias,
                                                    const float* __restrict__ res, int act,
                                                    float* __restrict__ dtf)
{
    __shared__ unsigned short As[2][128 * 32];
    __shared__ unsigned short Ws[2][128 * 32];
    const int tid = threadIdx.x;
    const int wave = tid >> 6;
    const int lane = tid & 63;
    const int m0 = blockIdx.x * 128;   // m fastest: XCD L2 A-sharing
    const int n0 = blockIdx.y * 128;
    const int wm = (wave & 1) * 64;
    const int wn = (wave >> 1) * 64;

    const size_t gA = (size_t)(m0 + 32 * wave + (lane >> 2)) * K + (lane & 3) * 8;
    const size_t gW = (size_t)(n0 + 32 * wave + (lane >> 2)) * K + (lane & 3) * 8;
    const int lofs = wave * 1024 + lane * 8;

    const int fr = lane & 15;
    const int fq = (lane >> 4) * 8;
    f32x4 acc[4][4] = {};

    for (int k0 = 0; k0 < K; k0 += 64) {
        glds16(A + gA + k0, As[0] + lofs);
        glds16(A + gA + (size_t)16 * K + k0, As[0] + lofs + 512);
        glds16(A + gA + k0 + 32, As[1] + lofs);
        glds16(A + gA + (size_t)16 * K + k0 + 32, As[1] + lofs + 512);
        glds16(W + gW + k0, Ws[0] + lofs);
        glds16(W + gW + (size_t)16 * K + k0, Ws[0] + lofs + 512);
        glds16(W + gW + k0 + 32, Ws[1] + lofs);
        glds16(W + gW + (size_t)16 * K + k0 + 32, Ws[1] + lofs + 512);
        __syncthreads();
#pragma unroll
        for (int p = 0; p < 2; p++) {
            bf16x8 af[4], bf[4];
#pragma unroll
            for (int mi = 0; mi < 4; mi++)
                af[mi] = *(const bf16x8*)(As[p] + (wm + mi * 16 + fr) * 32 + fq);
#pragma unroll
            for (int ni = 0; ni < 4; ni++)
                bf[ni] = *(const bf16x8*)(Ws[p] + (wn + ni * 16 + fr) * 32 + fq);
#pragma unroll
            for (int mi = 0; mi < 4; mi++)
#pragma unroll
                for (int ni = 0; ni < 4; ni++)
                    acc[mi][ni] = __builtin_amdgcn_mfma_f32_16x16x32_bf16(af[mi], bf[ni], acc[mi][ni], 0, 0, 0);
        }
        __syncthreads();
    }

    const int colb = n0 + wn + (lane & 15);
    const int rowb = m0 + wm + (lane >> 4) * 4;
#pragma unroll
    for (int mi = 0; mi < 4; mi++) {
#pragma unroll
        for (int ni = 0; ni < 4; ni++) {
            int col = colb + ni * 16;
            if (col < Nreal) {
#pragma unroll
                for (int r = 0; r < 4; r++) {
                    int row = rowb + mi * 16 + r;
                    float v = acc[mi][ni][r];
                    size_t idx = (size_t)row * Nreal + col;
                    if (bias) v += bias[col];
                    if (res) v += res[idx];
                    if (act) v = geluf(v);
                    if (Cb) {
                        Cb[idx] = f2bf(v);
                        if (dtf && col >= 2176) dtf[(size_t)row * 32 + (col - 2176)] = v;
                    } else Cf[idx] = v;
                }
            }
        }
    }
}

// ---------------- 64x64-tile GEMM, BK=64 twin-buffer (skinny-N tails) ----------------
__global__ __launch_bounds__(256) void gemm_bf16_t64(const unsigned short* __restrict__ A,
                                                     const unsigned short* __restrict__ W,
                                                     int K, int N,
                                                     float* __restrict__ Cf,
                                                     const float* __restrict__ bias,
                                                     const float* __restrict__ res)
{
    __shared__ unsigned short As[2][64 * 32];
    __shared__ unsigned short Ws[2][64 * 32];
    const int tid = threadIdx.x;
    const int wave = tid >> 6;
    const int lane = tid & 63;
    const int m0 = blockIdx.x * 64;
    const int n0 = blockIdx.y * 64;

    const size_t gA = (size_t)(m0 + (tid >> 2)) * K + (tid & 3) * 8;
    const size_t gW = (size_t)(n0 + (tid >> 2)) * K + (tid & 3) * 8;
    const int lofs = tid * 8;

    const int fr = lane & 15;
    const int fq = (lane >> 4) * 8;
    f32x4 acc[4] = {};

    for (int k0 = 0; k0 < K; k0 += 64) {
        glds16(A + gA + k0, As[0] + lofs);
        glds16(A + gA + k0 + 32, As[1] + lofs);
        glds16(W + gW + k0, Ws[0] + lofs);
        glds16(W + gW + k0 + 32, Ws[1] + lofs);
        __syncthreads();
#pragma unroll
        for (int p = 0; p < 2; p++) {
            bf16x8 af = *(const bf16x8*)(As[p] + (wave * 16 + fr) * 32 + fq);
#pragma unroll
            for (int ni = 0; ni < 4; ni++) {
                bf16x8 bfr = *(const bf16x8*)(Ws[p] + (ni * 16 + fr) * 32 + fq);
                acc[ni] = __builtin_amdgcn_mfma_f32_16x16x32_bf16(af, bfr, acc[ni], 0, 0, 0);
            }
        }
        __syncthreads();
    }

    const int col0 = n0 + (lane & 15);
    const int rowb = m0 + wave * 16 + (lane >> 4) * 4;
#pragma unroll
    for (int ni = 0; ni < 4; ni++) {
        int col = col0 + ni * 16;
        float bb = bias ? bias[col] : 0.f;
#pragma unroll
        for (int r = 0; r < 4; r++) {
            int row = rowb + r;
            size_t idx = (size_t)row * N + col;
            float v = acc[ni][r] + bb;
            if (res) v += res[idx];
            Cf[idx] = v;
        }
    }
}

// ---------------- depthwise causal conv: 4 channels x 8 timesteps per thread ----------------
__global__ __launch_bounds__(256) void conv_kernel(const unsigned short* __restrict__ zx,
                                                   const float* __restrict__ conv_w,
                                                   const float* __restrict__ conv_b,
                                                   unsigned short* __restrict__ out)
{
    int gid = blockIdx.x * 256 + threadIdx.x;
    int c4 = gid % 288;
    int tt = gid / 288;
    int c = c4 * 4;
    int b = tt >> 8;
    int t0 = (tt & 255) * 8;

    float wgt[4][7], bias[4];
#pragma unroll
    for (int q = 0; q < 4; q++) {
        bias[q] = conv_b[c + q];
#pragma unroll
        for (int j = 0; j < 7; j++) wgt[q][j] = conv_w[(c + q) * 7 + j];
    }

    float xin[4][14];
    const unsigned short* base = zx + (size_t)(b * SEQLEN + t0) * D_IN_PROJ + D_INNER + c;
#pragma unroll
    for (int j = 0; j < 14; j++) {
        int t = t0 - 6 + j;
        ushort4 v = make_ushort4(0, 0, 0, 0);
        if (t >= 0) v = *(const ushort4*)(base + (ptrdiff_t)(j - 6) * D_IN_PROJ);
        xin[0][j] = bf2f(v.x); xin[1][j] = bf2f(v.y);
        xin[2][j] = bf2f(v.z); xin[3][j] = bf2f(v.w);
    }

    unsigned short* orow = out + (size_t)(b * SEQLEN + t0) * CONV_DIM + c;
#pragma unroll
    for (int i = 0; i < 8; i++) {
        ushort4 o;
        float a0 = bias[0], a1 = bias[1], a2 = bias[2], a3 = bias[3];
#pragma unroll
        for (int j = 0; j < 7; j++) {
            a0 = fmaf(wgt[0][j], xin[0][i + j], a0);
            a1 = fmaf(wgt[1][j], xin[1][i + j], a1);
            a2 = fmaf(wgt[2][j], xin[2][i + j], a2);
            a3 = fmaf(wgt[3][j], xin[3][i + j], a3);
        }
        o.x = f2bf(siluf(a0)); o.y = f2bf(siluf(a1));
        o.z = f2bf(siluf(a2)); o.w = f2bf(siluf(a3));
        *(ushort4*)(orow + (size_t)i * CONV_DIM) = o;
    }
}

// ---------------- transpose xs: xbc_bf[:, :1024] -> xT[b][p][t] ----------------
__global__ __launch_bounds__(256) void xpose_kernel(const unsigned short* __restrict__ xbc,
                                                    unsigned short* __restrict__ xT)
{
    int tt = blockIdx.x, pt = blockIdx.y, b = blockIdx.z;
    __shared__ unsigned short T[64][68];
    {
        int r = threadIdx.x >> 4, q = threadIdx.x & 15;
#pragma unroll
        for (int i = 0; i < 4; i++) {
            int t = tt * 64 + r + i * 16;
            ushort4 v = *(const ushort4*)(xbc + (size_t)(b * SEQLEN + t) * CONV_DIM + pt * 64 + q * 4);
            *(ushort4*)&T[r + i * 16][q * 4] = v;
        }
    }
    __syncthreads();
    {
        int p = threadIdx.x >> 4, tq = threadIdx.x & 15;
#pragma unroll
        for (int i = 0; i < 4; i++) {
            int pp = p + i * 16;
            ushort4 o;
            o.x = T[tq * 4 + 0][pp]; o.y = T[tq * 4 + 1][pp];
            o.z = T[tq * 4 + 2][pp]; o.w = T[tq * 4 + 3][pp];
            *(ushort4*)(xT + ((size_t)b * 1024 + pt * 64 + pp) * 2048 + tt * 64 + tq * 4) = o;
        }
    }
}

// ---------------- dt/cum tables ----------------
__global__ __launch_bounds__(256) void dt_table_kernel(const float* __restrict__ dtf,
                                                       const float* __restrict__ dt_bias,
                                                       const float* __restrict__ A_log,
                                                       float* __restrict__ cum_tab,
                                                       float* __restrict__ dtv_tab)
{
    int wid = blockIdx.x * 4 + (threadIdx.x >> 6);
    int lane = threadIdx.x & 63;
    int c = wid & 31, h = (wid >> 5) & 15, b = (wid >> 9) & 3, d = wid >> 11;
    int tg = tglob(d, c, lane);
    float raw = dtf[(size_t)(b * SEQLEN + tg) * 32 + d * 16 + h] + dt_bias[h];
    float dtv = softplusf(raw);
    float cum = -expf(A_log[h]) * dtv;
#pragma unroll
    for (int off = 1; off < 64; off <<= 1) {
        int src = lane - off;
        float o = __shfl(cum, src < 0 ? 0 : src, 64);
        if (lane >= off) cum += o;
    }
    cum_tab[(size_t)wid * 64 + lane] = cum;
    dtv_tab[(size_t)wid * 64 + lane] = dtv;
}

// ---------------- K1: intra-chunk, MFMA (c==0 blocks also zero the boundary row) ----------------
__global__ __launch_bounds__(256) void ssd_intra_mfma(const unsigned short* __restrict__ xbc,
                                                      const unsigned short* __restrict__ xT,
                                                      const float* __restrict__ cum_tab,
                                                      const float* __restrict__ dtv_tab,
                                                      float* __restrict__ y_fw,
                                                      float* __restrict__ y_bw)
{
    const int bid = blockIdx.x;
    const int hq = bid & 3, c = (bid >> 2) & 31, b = (bid >> 7) & 3, d = bid >> 9;
    const int tid = threadIdx.x, wave = tid >> 6, lane = tid & 63;

    __shared__ unsigned short BnMt[64 * 80];
    __shared__ unsigned short CnXt[64 * 80];
    __shared__ float Gm[64 * 68];
    __shared__ float cum_l[64], dtv_l[64];

    if (c == 0) {   // unique owner of the boundary row slice (cols hq*256..hq*256+256)
        int t0 = d ? (SEQLEN - 1) : 0;
        float* ybuf = d ? y_bw : y_fw;
        ybuf[(size_t)(b * SEQLEN + t0) * D_INNER + hq * 256 + tid] = 0.f;
    }
    {
        int s = tid >> 2, nq = (tid & 3) * 16;
        int tg = tglob(d, c, s);
        const unsigned short* row = xbc + (size_t)(b * SEQLEN + tg) * CONV_DIM;
#pragma unroll
        for (int k = 0; k < 16; k += 4) {
            *(ushort4*)&BnMt[s * 80 + nq + k] = *(const ushort4*)(row + 1024 + nq + k);
            *(ushort4*)&CnXt[s * 80 + nq + k] = *(const ushort4*)(row + 1088 + nq + k);
        }
    }
    __syncthreads();
    {
        f32x4 ga[4] = {};
        const int mrow = wave * 16 + (lane & 15);
        const int kq = (lane >> 4) * 8;
#pragma unroll
        for (int k0 = 0; k0 < 64; k0 += 32) {
            bf16x8 afr = *(const bf16x8*)&BnMt[mrow * 80 + k0 + kq];
#pragma unroll
            for (int ni = 0; ni < 4; ni++) {
                bf16x8 bfr = *(const bf16x8*)&CnXt[(ni * 16 + (lane & 15)) * 80 + k0 + kq];
                ga[ni] = __builtin_amdgcn_mfma_f32_16x16x32_bf16(afr, bfr, ga[ni], 0, 0, 0);
            }
        }
        int col = lane & 15, quad = lane >> 4;
#pragma unroll
        for (int ni = 0; ni < 4; ni++)
#pragma unroll
            for (int r = 0; r < 4; r++)
                Gm[(wave * 16 + quad * 4 + r) * 68 + ni * 16 + col] = ga[ni][r];
    }

    for (int hh = 0; hh < 4; hh++) {
        const int h = hq * 4 + hh;
        __syncthreads();
        if (tid < 64) {
            int flat = ((d * 4 + b) * 16 + h) * 32 + c;
            cum_l[tid] = cum_tab[(size_t)flat * 64 + tid];
            dtv_l[tid] = dtv_tab[(size_t)flat * 64 + tid];
        }
        {
            const unsigned short* xrow = xT + ((size_t)b * 1024 + h * 64) * 2048;
            int p = tid >> 4, tq = tid & 15;
#pragma unroll
            for (int pi = 0; pi < 4; pi++, p += 16) {
                if (d == 0) {
                    ushort4 v = *(const ushort4*)(xrow + (size_t)p * 2048 + c * 64 + tq * 4);
                    *(ushort4*)&CnXt[p * 80 + tq * 4] = v;
                } else {
                    int base = SEQLEN - 64 - c * 64;
                    ushort4 v = *(const ushort4*)(xrow + (size_t)p * 2048 + base + (15 - tq) * 4);
                    CnXt[p * 80 + tq * 4 + 0] = v.w;
                    CnXt[p * 80 + tq * 4 + 1] = v.z;
                    CnXt[p * 80 + tq * 4 + 2] = v.y;
                    CnXt[p * 80 + tq * 4 + 3] = v.x;
                }
            }
        }
        __syncthreads();
        {
            int s = tid & 63, tq = tid >> 6;
            float cs = cum_l[s], dv = dtv_l[s];
#pragma unroll
            for (int j = 0; j < 16; j++) {
                int t = tq * 16 + j;
                float g = Gm[s * 68 + t];
                float m = (s <= t) ? g * expf(cum_l[t] - cs) * dv : 0.f;
                BnMt[t * 80 + s] = f2bf(m);
            }
        }
        __syncthreads();
        {
            f32x4 acc[4] = {};
            const int mrow = wave * 16 + (lane & 15);
            const int kq = (lane >> 4) * 8;
#pragma unroll
            for (int k0 = 0; k0 < 64; k0 += 32) {
                bf16x8 afr = *(const bf16x8*)&BnMt[mrow * 80 + k0 + kq];
#pragma unroll
                for (int ni = 0; ni < 4; ni++) {
                    bf16x8 bfr = *(const bf16x8*)&CnXt[(ni * 16 + (lane & 15)) * 80 + k0 + kq];
                    acc[ni] = __builtin_amdgcn_mfma_f32_16x16x32_bf16(afr, bfr, acc[ni], 0, 0, 0);
                }
            }
            float* ybuf = d ? y_bw : y_fw;
            int quad = lane >> 4, col0 = lane & 15;
#pragma unroll
            for (int r = 0; r < 4; r++) {
                int tl = wave * 16 + quad * 4 + r;
                int tg = tglob(d, c, tl);
                int tout = d ? (tg - 1) : (tg + 1);
                if (tout >= 0 && tout < SEQLEN) {
                    float* yp = ybuf + (size_t)(b * SEQLEN + tout) * D_INNER + h * 64;
#pragma unroll
                    for (int ni = 0; ni < 4; ni++)
                        yp[ni * 16 + col0] = acc[ni][r];
                }
            }
        }
    }
}

// ---------------- K2: per-chunk state S'[p][n] -> bf16 tiles ----------------
__global__ __launch_bounds__(256) void ssd_state_kernel(const unsigned short* __restrict__ xbc,
                                                        const float* __restrict__ cum_tab,
                                                        const float* __restrict__ dtv_tab,
                                                        unsigned short* __restrict__ sreg16)
{
    const int flat = blockIdx.x;
    const int c = flat & 31, h = (flat >> 5) & 15, b = (flat >> 9) & 3, d = flat >> 11;
    const int tid = threadIdx.x;
    const int ty = tid >> 4, tx = tid & 15;

    __shared__ float Bm[64][64];
    __shared__ float Xw[64][64];
    __shared__ float cum_l[64], dtv_l[64];

    if (tid < 64) {
        cum_l[tid] = cum_tab[(size_t)flat * 64 + tid];
        dtv_l[tid] = dtv_tab[(size_t)flat * 64 + tid];
    }
    __syncthreads();
    float clast = cum_l[63];
    for (int idx = tid; idx < 1024; idx += 256) {
        int s = idx >> 4, q = idx & 15;
        int tg = tglob(d, c, s);
        const unsigned short* row = xbc + (size_t)(b * SEQLEN + tg) * CONV_DIM;
        ushort4 ub = *(const ushort4*)(row + 1024 + q * 4);
        ushort4 ux = *(const ushort4*)(row + h * 64 + q * 4);
        float w = expf(clast - cum_l[s]) * dtv_l[s];
        Bm[s][q*4+0] = bf2f(ub.x); Bm[s][q*4+1] = bf2f(ub.y);
        Bm[s][q*4+2] = bf2f(ub.z); Bm[s][q*4+3] = bf2f(ub.w);
        Xw[s][q*4+0] = bf2f(ux.x)*w; Xw[s][q*4+1] = bf2f(ux.y)*w;
        Xw[s][q*4+2] = bf2f(ux.z)*w; Xw[s][q*4+3] = bf2f(ux.w)*w;
    }
    __syncthreads();
    float acc[4][4] = {};
    for (int s = 0; s < 64; s++) {
        float4 xv = *(const float4*)&Xw[s][ty * 4];
        float4 bv = *(const float4*)&Bm[s][tx * 4];
        float xx[4] = {xv.x, xv.y, xv.z, xv.w};
        float bb[4] = {bv.x, bv.y, bv.z, bv.w};
#pragma unroll
        for (int i = 0; i < 4; i++)
#pragma unroll
            for (int j = 0; j < 4; j++) acc[i][j] = fmaf(xx[i], bb[j], acc[i][j]);
    }
    unsigned short* st = sreg16 + (size_t)flat * 4096;
#pragma unroll
    for (int i = 0; i < 4; i++) {
        ushort4 o;
        o.x = f2bf(acc[i][0]); o.y = f2bf(acc[i][1]);
        o.z = f2bf(acc[i][2]); o.w = f2bf(acc[i][3]);
        *(ushort4*)&st[(size_t)(ty * 4 + i) * 64 + tx * 4] = o;
    }
}

// ---------------- K3: serial chunk scan ----------------
__global__ __launch_bounds__(256) void ssd_chunkscan_kernel(const float* __restrict__ cum_tab,
                                                            unsigned short* __restrict__ sreg16)
{
    const int ps = blockIdx.x & 3;
    const int g  = blockIdx.x >> 2;
    const int tid = threadIdx.x;
    const int base = g * 32;
    const size_t off = (size_t)ps * 1024 + tid * 4;
    float h0 = 0.f, h1 = 0.f, h2 = 0.f, h3 = 0.f;
    ushort4 s = *(ushort4*)(sreg16 + (size_t)base * 4096 + off);
    for (int c = 0; c < 32; c++) {
        int flat = base + c;
        ushort4 snext;
        if (c < 31) snext = *(ushort4*)(sreg16 + (size_t)(flat + 1) * 4096 + off);
        float dec = expf(cum_tab[(size_t)flat * 64 + 63]);
        ushort4 o;
        o.x = f2bf(h0); o.y = f2bf(h1); o.z = f2bf(h2); o.w = f2bf(h3);
        *(ushort4*)(sreg16 + (size_t)flat * 4096 + off) = o;
        h0 = h0 * dec + bf2f(s.x);
        h1 = h1 * dec + bf2f(s.y);
        h2 = h2 * dec + bf2f(s.z);
        h3 = h3 * dec + bf2f(s.w);
        s = snext;
    }
}

// ---------------- K4: inter-chunk, MFMA ----------------
__global__ __launch_bounds__(256) void ssd_inter_mfma(const unsigned short* __restrict__ xbc,
                                                      const float* __restrict__ cum_tab,
                                                      const unsigned short* __restrict__ sreg16,
                                                      float* __restrict__ y_fw,
                                                      float* __restrict__ y_bw)
{
    const int flat = blockIdx.x;
    const int c = flat & 31;
    if (c == 0) return;
    const int h = (flat >> 5) & 15, b = (flat >> 9) & 3, d = flat >> 11;
    const int tid = threadIdx.x, wave = tid >> 6, lane = tid & 63;

    __shared__ unsigned short Cs[64 * 72];
    __shared__ unsigned short Hs[64 * 72];
    __shared__ float cum_l[64];

    if (tid < 64) cum_l[tid] = cum_tab[(size_t)flat * 64 + tid];
    {
        int s = tid >> 2, nq = (tid & 3) * 16;
        int tg = tglob(d, c, s);
        const unsigned short* row = xbc + (size_t)(b * SEQLEN + tg) * CONV_DIM + 1088;
        const unsigned short* st = sreg16 + (size_t)flat * 4096 + s * 64;
#pragma unroll
        for (int k = 0; k < 16; k += 4) {
            *(ushort4*)&Cs[s * 72 + nq + k] = *(const ushort4*)(row + nq + k);
            *(ushort4*)&Hs[s * 72 + nq + k] = *(const ushort4*)(st + nq + k);
        }
    }
    __syncthreads();
    f32x4 acc[4] = {};
    const int fr = lane & 15, kq = (lane >> 4) * 8;
    const int mrow = wave * 16 + fr;
#pragma unroll
    for (int k0 = 0; k0 < 64; k0 += 32) {
        bf16x8 afr = *(const bf16x8*)&Cs[mrow * 72 + k0 + kq];
#pragma unroll
        for (int ni = 0; ni < 4; ni++) {
            bf16x8 bfr = *(const bf16x8*)&Hs[(ni * 16 + fr) * 72 + k0 + kq];
            acc[ni] = __builtin_amdgcn_mfma_f32_16x16x32_bf16(afr, bfr, acc[ni], 0, 0, 0);
        }
    }
    float* ybuf = d ? y_bw : y_fw;
    int quad = lane >> 4, col0 = lane & 15;
#pragma unroll
    for (int r = 0; r < 4; r++) {
        int tl = wave * 16 + quad * 4 + r;
        float a = expf(cum_l[tl]);
        int tg = tglob(d, c, tl);
        int tout = d ? (tg - 1) : (tg + 1);
        if (tout >= 0 && tout < SEQLEN) {
            float* yp = ybuf + (size_t)(b * SEQLEN + tout) * D_INNER + h * 64;
#pragma unroll
            for (int ni = 0; ni < 4; ni++)
                yp[ni * 16 + col0] += acc[ni][r] * a;
        }
    }
}

// ---------------- combine -> bf16 yg ----------------
__global__ __launch_bounds__(256) void combine_kernel(const unsigned short* __restrict__ zx,
                                                      const unsigned short* __restrict__ xbc,
                                                      const float* __restrict__ y_fw,
                                                      const float* __restrict__ y_bw,
                                                      const float* __restrict__ Dp,
                                                      const float* __restrict__ rms_w,
                                                      unsigned short* __restrict__ yg)
{
    int row = blockIdx.x;
    int i = threadIdx.x * 4;
    float4 yf = *(const float4*)(y_fw + (size_t)row * D_INNER + i);
    float4 yb = *(const float4*)(y_bw + (size_t)row * D_INNER + i);
    ushort4 uxs = *(const ushort4*)(xbc + (size_t)row * CONV_DIM + i);
    ushort4 uz  = *(const ushort4*)(zx + (size_t)row * D_IN_PROJ + i);
    float dp = Dp[i >> 6];
    float g[4];
    g[0] = (yf.x + yb.x + bf2f(uxs.x) * dp) * siluf(bf2f(uz.x));
    g[1] = (yf.y + yb.y + bf2f(uxs.y) * dp) * siluf(bf2f(uz.y));
    g[2] = (yf.z + yb.z + bf2f(uxs.z) * dp) * siluf(bf2f(uz.z));
    g[3] = (yf.w + yb.w + bf2f(uxs.w) * dp) * siluf(bf2f(uz.w));
    float ss = g[0]*g[0] + g[1]*g[1] + g[2]*g[2] + g[3]*g[3];
#pragma unroll
    for (int m = 1; m < 64; m <<= 1) ss += __shfl_xor(ss, m, 64);
    __shared__ float red[4];
    if ((threadIdx.x & 63) == 0) red[threadIdx.x >> 6] = ss;
    __syncthreads();
    ss = red[0] + red[1] + red[2] + red[3];
    float scale = rsqrtf(ss * (1.f / D_INNER) + EPS);
    float4 rw = *(const float4*)(rms_w + i);
    ushort4 o;
    o.x = f2bf(g[0] * scale * rw.x); o.y = f2bf(g[1] * scale * rw.y);
    o.z = f2bf(g[2] * scale * rw.z); o.w = f2bf(g[3] * scale * rw.w);
    *(ushort4*)(yg + (size_t)row * D_INNER + i) = o;
}

// ---------------- launch ----------------
extern "C" void kernel_launch(void* const* d_in, const int* in_sizes, int n_in,
                              void* d_out, int out_size, void* d_ws, size_t ws_size,
                              hipStream_t stream)
{
    const float* x         = (const float*)d_in[0];
    const float* ln1_w     = (const float*)d_in[1];
    const float* ln1_b     = (const float*)d_in[2];
    const float* in_proj_w = (const float*)d_in[3];
    const float* conv_w    = (const float*)d_in[4];
    const float* conv_b    = (const float*)d_in[5];
    const float* dt_bias   = (const float*)d_in[6];
    const float* A_log     = (const float*)d_in[7];
    const float* Dp        = (const float*)d_in[8];
    const float* rms_w     = (const float*)d_in[9];
    const float* out_proj_w= (const float*)d_in[10];
    const float* ln2_w     = (const float*)d_in[11];
    const float* ln2_b     = (const float*)d_in[12];
    const float* fc1_w     = (const float*)d_in[13];
    const float* fc1_b     = (const float*)d_in[14];
    const float* fc2_w     = (const float*)d_in[15];
    const float* fc2_b     = (const float*)d_in[16];
    float* out = (float*)d_out;

    float* ws0 = (float*)d_ws;
    unsigned short* zx_bf  = (unsigned short*)ws0;
    unsigned short* xbc_bf = (unsigned short*)(ws0 + OFF_XBCB);
    unsigned short* xT_bf  = (unsigned short*)(ws0 + OFF_XT);
    float* y_fw = ws0 + OFF_YFW;
    float* y_bw = ws0 + OFF_YBW;
    float* sreg = ws0 + OFF_SREG;
    unsigned short* sreg16 = (unsigned short*)sreg;
    unsigned short* hA_bf = (unsigned short*)sreg;
    unsigned short* yg_bf = (unsigned short*)(sreg + 2686976);
    float* x_res          = sreg + 6881280;
    unsigned short* sh    = (unsigned short*)sreg;
    unsigned short* P_in  = sh + 22151168;
    unsigned short* P_out = sh + 23330816;
    unsigned short* P_f1  = sh + 23855104;
    unsigned short* P_f2  = sh + 24903680;
    unsigned short* f1_bf = (unsigned short*)ws0;
    float* cum_tab = out;
    float* dtv_tab = out + 262144;
    float* dtf     = out + 524288;

    // 0. all weight conversions, one launch
    wconv_all<<<dim3(3712), dim3(256), 0, stream>>>(in_proj_w, P_in, out_proj_w, P_out, fc1_w, P_f1, fc2_w, P_f2);
    // 1. LN1 -> bf16
    ln_kernel<<<dim3(NTOK / 4), dim3(256), 0, stream>>>(x, ln1_w, ln1_b, hA_bf, NTOK);
    // 2. in_proj -> bf16 zx (+ fp32 dt sidecar)
    gemm_bf16<<<dim3(64, 18), dim3(256), 0, stream>>>(hA_bf, P_in, 512, 2208, nullptr, zx_bf, nullptr, nullptr, 0, dtf);
    // 3. conv (register-tiled 4c x 8t)
    conv_kernel<<<dim3(288 * 1024 / 256), dim3(256), 0, stream>>>(zx_bf, conv_w, conv_b, xbc_bf);
    // 4. transpose
    xpose_kernel<<<dim3(32, 16, 4), dim3(256), 0, stream>>>(xbc_bf, xT_bf);
    // 5. tables
    dt_table_kernel<<<dim3(1024), dim3(256), 0, stream>>>(dtf, dt_bias, A_log, cum_tab, dtv_tab);
    // 6. SSD (intra zeroes boundary rows)
    ssd_intra_mfma<<<dim3(1024), dim3(256), 0, stream>>>(xbc_bf, xT_bf, cum_tab, dtv_tab, y_fw, y_bw);
    ssd_state_kernel<<<dim3(4096), dim3(256), 0, stream>>>(xbc_bf, cum_tab, dtv_tab, sreg16);
    ssd_chunkscan_kernel<<<dim3(512), dim3(256), 0, stream>>>(cum_tab, sreg16);
    ssd_inter_mfma<<<dim3(4096), dim3(256), 0, stream>>>(xbc_bf, cum_tab, sreg16, y_fw, y_bw);
    // 7. combine -> bf16 yg
    combine_kernel<<<dim3(NTOK), dim3(256), 0, stream>>>(zx_bf, xbc_bf, y_fw, y_bw, Dp, rms_w, yg_bf);
    // 8. out_proj + residual(x) -> x_res
    gemm_bf16_t64<<<dim3(128, 8), dim3(256), 0, stream>>>(yg_bf, P_out, 1024, 512, x_res, nullptr, x);
    // 9. LN2 -> bf16
    ln_kernel<<<dim3(NTOK / 4), dim3(256), 0, stream>>>(x_res, ln2_w, ln2_b, hA_bf, NTOK);
    // 10. fc1 + bias + GELU -> bf16
    gemm_bf16<<<dim3(64, 16), dim3(256), 0, stream>>>(hA_bf, P_f1, 512, 2048, nullptr, f1_bf, fc1_b, nullptr, 1, nullptr);
    // 11. fc2 + bias + residual(x_res) -> out
    gemm_bf16_t64<<<dim3(128, 8), dim3(256), 0, stream>>>(f1_bf, P_f2, 2048, 512, out, fc2_b, x_res);
}

// Round 11
// 379.672 us; speedup vs baseline: 1.4094x; 1.0472x over previous
//
#include <hip/hip_runtime.h>
#include <math.h>

#define D_MODEL   512
#define D_INNER   1024
#define NHEADS    16
#define HEADDIM   64
#define D_STATE   64
#define D_CONV    7
#define D_FF      2048
#define CONV_DIM  1152
#define D_IN_PROJ 2208
#define BATCH     4
#define SEQLEN    2048
#define NTOK      (BATCH*SEQLEN)
#define EPS       1e-5f

// ---- workspace layout (float32 units) ----  (see R5/R6/R9 journal)
#define OFF_XBCB  9043968ull
#define OFF_XT    13762560ull
#define OFF_YFW   17956864ull
#define OFF_YBW   26345472ull
#define OFF_SREG  34734080ull

typedef __bf16 bf16x8 __attribute__((ext_vector_type(8)));
typedef float  f32x4  __attribute__((ext_vector_type(4)));

__device__ __forceinline__ float siluf(float x) { return x / (1.f + expf(-x)); }
__device__ __forceinline__ float geluf(float x) { return 0.5f * x * (1.f + erff(x * 0.70710678118654752f)); }
__device__ __forceinline__ float softplusf(float x) { return fmaxf(x, 0.f) + log1pf(expf(-fabsf(x))); }
__device__ __forceinline__ int tglob(int d, int c, int t) { int s = c * 64 + t; return d ? (SEQLEN - 1 - s) : s; }
__device__ __forceinline__ unsigned short f2bf(float f) {
    unsigned int u = __float_as_uint(f);
    u += 0x7FFFu + ((u >> 16) & 1u);
    return (unsigned short)(u >> 16);
}
__device__ __forceinline__ float bf2f(unsigned short u) { return __uint_as_float((unsigned)u << 16); }
__device__ __forceinline__ void glds16(const void* g, void* l) {
    __builtin_amdgcn_global_load_lds((const __attribute__((address_space(1))) void*)g,
                                     (__attribute__((address_space(3))) void*)l, 16, 0, 0);
}

// ---------------- LayerNorm -> bf16 ----------------
__global__ __launch_bounds__(256) void ln_kernel(const float* __restrict__ x,
                                                 const float* __restrict__ w,
                                                 const float* __restrict__ b,
                                                 unsigned short* __restrict__ out, int nrows)
{
    int wid = threadIdx.x >> 6;
    int lane = threadIdx.x & 63;
    int row = blockIdx.x * 4 + wid;
    if (row >= nrows) return;
    const float* xr = x + (size_t)row * D_MODEL;
    float4 v0 = *(const float4*)(xr + lane * 8);
    float4 v1 = *(const float4*)(xr + lane * 8 + 4);
    float v[8] = {v0.x, v0.y, v0.z, v0.w, v1.x, v1.y, v1.z, v1.w};
    float s = 0.f;
#pragma unroll
    for (int i = 0; i < 8; i++) s += v[i];
#pragma unroll
    for (int m = 1; m < 64; m <<= 1) s += __shfl_xor(s, m, 64);
    float mu = s * (1.f / D_MODEL);
    float q = 0.f;
#pragma unroll
    for (int i = 0; i < 8; i++) { float dd = v[i] - mu; q += dd * dd; }
#pragma unroll
    for (int m = 1; m < 64; m <<= 1) q += __shfl_xor(q, m, 64);
    float inv = rsqrtf(q * (1.f / D_MODEL) + EPS);
    float4 w0 = *(const float4*)(w + lane * 8);
    float4 w1 = *(const float4*)(w + lane * 8 + 4);
    float4 b0 = *(const float4*)(b + lane * 8);
    float4 b1 = *(const float4*)(b + lane * 8 + 4);
    float o[8];
    o[0] = (v[0]-mu)*inv*w0.x + b0.x; o[1] = (v[1]-mu)*inv*w0.y + b0.y;
    o[2] = (v[2]-mu)*inv*w0.z + b0.z; o[3] = (v[3]-mu)*inv*w0.w + b0.w;
    o[4] = (v[4]-mu)*inv*w1.x + b1.x; o[5] = (v[5]-mu)*inv*w1.y + b1.y;
    o[6] = (v[6]-mu)*inv*w1.z + b1.z; o[7] = (v[7]-mu)*inv*w1.w + b1.w;
    unsigned short* orow = out + (size_t)row * D_MODEL + lane * 8;
    ushort4 p0, p1;
    p0.x = f2bf(o[0]); p0.y = f2bf(o[1]); p0.z = f2bf(o[2]); p0.w = f2bf(o[3]);
    p1.x = f2bf(o[4]); p1.y = f2bf(o[5]); p1.z = f2bf(o[6]); p1.w = f2bf(o[7]);
    *(ushort4*)orow = p0;
    *(ushort4*)(orow + 4) = p1;
}

// ---------------- all weight fp32 -> bf16 pads, one launch ----------------
__global__ __launch_bounds__(256) void wconv_all(const float* __restrict__ w0, unsigned short* __restrict__ p0,
                                                 const float* __restrict__ w1, unsigned short* __restrict__ p1,
                                                 const float* __restrict__ w2, unsigned short* __restrict__ p2,
                                                 const float* __restrict__ w3, unsigned short* __restrict__ p3)
{
    int i = blockIdx.x * 256 + threadIdx.x;
    const float* src; unsigned short* dst; int srcn;
    if (i < 294912)      { src = w0; dst = p0; srcn = 282624; }
    else if (i < 425984) { i -= 294912; src = w1; dst = p1; srcn = 131072; }
    else if (i < 688128) { i -= 425984; src = w2; dst = p2; srcn = 262144; }
    else                 { i -= 688128; src = w3; dst = p3; srcn = 262144; }
    ushort4 o = make_ushort4(0, 0, 0, 0);
    if (i < srcn) {
        float4 v = ((const float4*)src)[i];
        o.x = f2bf(v.x); o.y = f2bf(v.y); o.z = f2bf(v.z); o.w = f2bf(v.w);
    }
    ((ushort4*)dst)[i] = o;
}

// ---------------- bf16 MFMA GEMM: BK=64 twin-buffer + XOR bank swizzle ----------------
// Staging fetches k-chunk (l&3)^((l>>3)&3) so LDS rows hold swizzled chunks;
// fragment reads compensate with q^((fr>>1)&3) -> 2-way bank aliasing (free).
__global__ __launch_bounds__(256, 2) void gemm_bf16(const unsigned short* __restrict__ A,
                                                    const unsigned short* __restrict__ W,
                                                    int K, int Nreal,
                                                    float* __restrict__ Cf,
                                                    unsigned short* __restrict__ Cb,
                                                    const float* __restrict__ bias,
                                                    const float* __restrict__ res, int act,
                                                    float* __restrict__ dtf)
{
    __shared__ unsigned short As[2][128 * 32];
    __shared__ unsigned short Ws[2][128 * 32];
    const int tid = threadIdx.x;
    const int wave = tid >> 6;
    const int lane = tid & 63;
    const int m0 = blockIdx.x * 128;
    const int n0 = blockIdx.y * 128;
    const int wm = (wave & 1) * 64;
    const int wn = (wave >> 1) * 64;

    const int kchunk = ((lane & 3) ^ ((lane >> 3) & 3)) * 8;   // swizzled fetch chunk
    const size_t gA = (size_t)(m0 + 32 * wave + (lane >> 2)) * K + kchunk;
    const size_t gW = (size_t)(n0 + 32 * wave + (lane >> 2)) * K + kchunk;
    const int lofs = wave * 1024 + lane * 8;

    const int fr = lane & 15;
    const int fq = ((lane >> 4) ^ ((fr >> 1) & 3)) * 8;        // de-swizzled read chunk
    f32x4 acc[4][4] = {};

    for (int k0 = 0; k0 < K; k0 += 64) {
        glds16(A + gA + k0, As[0] + lofs);
        glds16(A + gA + (size_t)16 * K + k0, As[0] + lofs + 512);
        glds16(A + gA + k0 + 32, As[1] + lofs);
        glds16(A + gA + (size_t)16 * K + k0 + 32, As[1] + lofs + 512);
        glds16(W + gW + k0, Ws[0] + lofs);
        glds16(W + gW + (size_t)16 * K + k0, Ws[0] + lofs + 512);
        glds16(W + gW + k0 + 32, Ws[1] + lofs);
        glds16(W + gW + (size_t)16 * K + k0 + 32, Ws[1] + lofs + 512);
        __syncthreads();
#pragma unroll
        for (int p = 0; p < 2; p++) {
            bf16x8 af[4], bf[4];
#pragma unroll
            for (int mi = 0; mi < 4; mi++)
                af[mi] = *(const bf16x8*)(As[p] + (wm + mi * 16 + fr) * 32 + fq);
#pragma unroll
            for (int ni = 0; ni < 4; ni++)
                bf[ni] = *(const bf16x8*)(Ws[p] + (wn + ni * 16 + fr) * 32 + fq);
#pragma unroll
            for (int mi = 0; mi < 4; mi++)
#pragma unroll
                for (int ni = 0; ni < 4; ni++)
                    acc[mi][ni] = __builtin_amdgcn_mfma_f32_16x16x32_bf16(af[mi], bf[ni], acc[mi][ni], 0, 0, 0);
        }
        __syncthreads();
    }

    const int colb = n0 + wn + (lane & 15);
    const int rowb = m0 + wm + (lane >> 4) * 4;
#pragma unroll
    for (int mi = 0; mi < 4; mi++) {
#pragma unroll
        for (int ni = 0; ni < 4; ni++) {
            int col = colb + ni * 16;
            if (col < Nreal) {
#pragma unroll
                for (int r = 0; r < 4; r++) {
                    int row = rowb + mi * 16 + r;
                    float v = acc[mi][ni][r];
                    size_t idx = (size_t)row * Nreal + col;
                    if (bias) v += bias[col];
                    if (res) v += res[idx];
                    if (act) v = geluf(v);
                    if (Cb) {
                        Cb[idx] = f2bf(v);
                        if (dtf && col >= 2176) dtf[(size_t)row * 32 + (col - 2176)] = v;
                    } else Cf[idx] = v;
                }
            }
        }
    }
}

// ---------------- 64x64-tile GEMM, BK=64 twin-buffer + XOR swizzle ----------------
__global__ __launch_bounds__(256) void gemm_bf16_t64(const unsigned short* __restrict__ A,
                                                     const unsigned short* __restrict__ W,
                                                     int K, int N,
                                                     float* __restrict__ Cf,
                                                     const float* __restrict__ bias,
                                                     const float* __restrict__ res)
{
    __shared__ unsigned short As[2][64 * 32];
    __shared__ unsigned short Ws[2][64 * 32];
    const int tid = threadIdx.x;
    const int wave = tid >> 6;
    const int lane = tid & 63;
    const int m0 = blockIdx.x * 64;
    const int n0 = blockIdx.y * 64;

    const int kchunk = ((tid & 3) ^ ((tid >> 3) & 3)) * 8;
    const size_t gA = (size_t)(m0 + (tid >> 2)) * K + kchunk;
    const size_t gW = (size_t)(n0 + (tid >> 2)) * K + kchunk;
    const int lofs = tid * 8;

    const int fr = lane & 15;
    const int fq = ((lane >> 4) ^ ((fr >> 1) & 3)) * 8;
    f32x4 acc[4] = {};

    for (int k0 = 0; k0 < K; k0 += 64) {
        glds16(A + gA + k0, As[0] + lofs);
        glds16(A + gA + k0 + 32, As[1] + lofs);
        glds16(W + gW + k0, Ws[0] + lofs);
        glds16(W + gW + k0 + 32, Ws[1] + lofs);
        __syncthreads();
#pragma unroll
        for (int p = 0; p < 2; p++) {
            bf16x8 af = *(const bf16x8*)(As[p] + (wave * 16 + fr) * 32 + fq);
#pragma unroll
            for (int ni = 0; ni < 4; ni++) {
                bf16x8 bfr = *(const bf16x8*)(Ws[p] + (ni * 16 + fr) * 32 + fq);
                acc[ni] = __builtin_amdgcn_mfma_f32_16x16x32_bf16(af, bfr, acc[ni], 0, 0, 0);
            }
        }
        __syncthreads();
    }

    const int col0 = n0 + (lane & 15);
    const int rowb = m0 + wave * 16 + (lane >> 4) * 4;
#pragma unroll
    for (int ni = 0; ni < 4; ni++) {
        int col = col0 + ni * 16;
        float bb = bias ? bias[col] : 0.f;
#pragma unroll
        for (int r = 0; r < 4; r++) {
            int row = rowb + r;
            size_t idx = (size_t)row * N + col;
            float v = acc[ni][r] + bb;
            if (res) v += res[idx];
            Cf[idx] = v;
        }
    }
}

// ---------------- depthwise causal conv: 4 channels x 8 timesteps per thread ----------------
__global__ __launch_bounds__(256) void conv_kernel(const unsigned short* __restrict__ zx,
                                                   const float* __restrict__ conv_w,
                                                   const float* __restrict__ conv_b,
                                                   unsigned short* __restrict__ out)
{
    int gid = blockIdx.x * 256 + threadIdx.x;
    int c4 = gid % 288;
    int tt = gid / 288;
    int c = c4 * 4;
    int b = tt >> 8;
    int t0 = (tt & 255) * 8;

    float wgt[4][7], bias[4];
#pragma unroll
    for (int q = 0; q < 4; q++) {
        bias[q] = conv_b[c + q];
#pragma unroll
        for (int j = 0; j < 7; j++) wgt[q][j] = conv_w[(c + q) * 7 + j];
    }

    float xin[4][14];
    const unsigned short* base = zx + (size_t)(b * SEQLEN + t0) * D_IN_PROJ + D_INNER + c;
#pragma unroll
    for (int j = 0; j < 14; j++) {
        int t = t0 - 6 + j;
        ushort4 v = make_ushort4(0, 0, 0, 0);
        if (t >= 0) v = *(const ushort4*)(base + (ptrdiff_t)(j - 6) * D_IN_PROJ);
        xin[0][j] = bf2f(v.x); xin[1][j] = bf2f(v.y);
        xin[2][j] = bf2f(v.z); xin[3][j] = bf2f(v.w);
    }

    unsigned short* orow = out + (size_t)(b * SEQLEN + t0) * CONV_DIM + c;
#pragma unroll
    for (int i = 0; i < 8; i++) {
        ushort4 o;
        float a0 = bias[0], a1 = bias[1], a2 = bias[2], a3 = bias[3];
#pragma unroll
        for (int j = 0; j < 7; j++) {
            a0 = fmaf(wgt[0][j], xin[0][i + j], a0);
            a1 = fmaf(wgt[1][j], xin[1][i + j], a1);
            a2 = fmaf(wgt[2][j], xin[2][i + j], a2);
            a3 = fmaf(wgt[3][j], xin[3][i + j], a3);
        }
        o.x = f2bf(siluf(a0)); o.y = f2bf(siluf(a1));
        o.z = f2bf(siluf(a2)); o.w = f2bf(siluf(a3));
        *(ushort4*)(orow + (size_t)i * CONV_DIM) = o;
    }
}

// ---------------- transpose xs: xbc_bf[:, :1024] -> xT[b][p][t] ----------------
__global__ __launch_bounds__(256) void xpose_kernel(const unsigned short* __restrict__ xbc,
                                                    unsigned short* __restrict__ xT)
{
    int tt = blockIdx.x, pt = blockIdx.y, b = blockIdx.z;
    __shared__ unsigned short T[64][68];
    {
        int r = threadIdx.x >> 4, q = threadIdx.x & 15;
#pragma unroll
        for (int i = 0; i < 4; i++) {
            int t = tt * 64 + r + i * 16;
            ushort4 v = *(const ushort4*)(xbc + (size_t)(b * SEQLEN + t) * CONV_DIM + pt * 64 + q * 4);
            *(ushort4*)&T[r + i * 16][q * 4] = v;
        }
    }
    __syncthreads();
    {
        int p = threadIdx.x >> 4, tq = threadIdx.x & 15;
#pragma unroll
        for (int i = 0; i < 4; i++) {
            int pp = p + i * 16;
            ushort4 o;
            o.x = T[tq * 4 + 0][pp]; o.y = T[tq * 4 + 1][pp];
            o.z = T[tq * 4 + 2][pp]; o.w = T[tq * 4 + 3][pp];
            *(ushort4*)(xT + ((size_t)b * 1024 + pt * 64 + pp) * 2048 + tt * 64 + tq * 4) = o;
        }
    }
}

// ---------------- dt/cum tables ----------------
__global__ __launch_bounds__(256) void dt_table_kernel(const float* __restrict__ dtf,
                                                       const float* __restrict__ dt_bias,
                                                       const float* __restrict__ A_log,
                                                       float* __restrict__ cum_tab,
                                                       float* __restrict__ dtv_tab)
{
    int wid = blockIdx.x * 4 + (threadIdx.x >> 6);
    int lane = threadIdx.x & 63;
    int c = wid & 31, h = (wid >> 5) & 15, b = (wid >> 9) & 3, d = wid >> 11;
    int tg = tglob(d, c, lane);
    float raw = dtf[(size_t)(b * SEQLEN + tg) * 32 + d * 16 + h] + dt_bias[h];
    float dtv = softplusf(raw);
    float cum = -expf(A_log[h]) * dtv;
#pragma unroll
    for (int off = 1; off < 64; off <<= 1) {
        int src = lane - off;
        float o = __shfl(cum, src < 0 ? 0 : src, 64);
        if (lane >= off) cum += o;
    }
    cum_tab[(size_t)wid * 64 + lane] = cum;
    dtv_tab[(size_t)wid * 64 + lane] = dtv;
}

// ---------------- K1: intra-chunk, MFMA (c==0 blocks also zero the boundary row) ----------------
__global__ __launch_bounds__(256) void ssd_intra_mfma(const unsigned short* __restrict__ xbc,
                                                      const unsigned short* __restrict__ xT,
                                                      const float* __restrict__ cum_tab,
                                                      const float* __restrict__ dtv_tab,
                                                      float* __restrict__ y_fw,
                                                      float* __restrict__ y_bw)
{
    const int bid = blockIdx.x;
    const int hq = bid & 3, c = (bid >> 2) & 31, b = (bid >> 7) & 3, d = bid >> 9;
    const int tid = threadIdx.x, wave = tid >> 6, lane = tid & 63;

    __shared__ unsigned short BnMt[64 * 80];
    __shared__ unsigned short CnXt[64 * 80];
    __shared__ float Gm[64 * 68];
    __shared__ float cum_l[64], dtv_l[64];

    if (c == 0) {
        int t0 = d ? (SEQLEN - 1) : 0;
        float* ybuf = d ? y_bw : y_fw;
        ybuf[(size_t)(b * SEQLEN + t0) * D_INNER + hq * 256 + tid] = 0.f;
    }
    {
        int s = tid >> 2, nq = (tid & 3) * 16;
        int tg = tglob(d, c, s);
        const unsigned short* row = xbc + (size_t)(b * SEQLEN + tg) * CONV_DIM;
#pragma unroll
        for (int k = 0; k < 16; k += 4) {
            *(ushort4*)&BnMt[s * 80 + nq + k] = *(const ushort4*)(row + 1024 + nq + k);
            *(ushort4*)&CnXt[s * 80 + nq + k] = *(const ushort4*)(row + 1088 + nq + k);
        }
    }
    __syncthreads();
    {
        f32x4 ga[4] = {};
        const int mrow = wave * 16 + (lane & 15);
        const int kq = (lane >> 4) * 8;
#pragma unroll
        for (int k0 = 0; k0 < 64; k0 += 32) {
            bf16x8 afr = *(const bf16x8*)&BnMt[mrow * 80 + k0 + kq];
#pragma unroll
            for (int ni = 0; ni < 4; ni++) {
                bf16x8 bfr = *(const bf16x8*)&CnXt[(ni * 16 + (lane & 15)) * 80 + k0 + kq];
                ga[ni] = __builtin_amdgcn_mfma_f32_16x16x32_bf16(afr, bfr, ga[ni], 0, 0, 0);
            }
        }
        int col = lane & 15, quad = lane >> 4;
#pragma unroll
        for (int ni = 0; ni < 4; ni++)
#pragma unroll
            for (int r = 0; r < 4; r++)
                Gm[(wave * 16 + quad * 4 + r) * 68 + ni * 16 + col] = ga[ni][r];
    }

    for (int hh = 0; hh < 4; hh++) {
        const int h = hq * 4 + hh;
        __syncthreads();
        if (tid < 64) {
            int flat = ((d * 4 + b) * 16 + h) * 32 + c;
            cum_l[tid] = cum_tab[(size_t)flat * 64 + tid];
            dtv_l[tid] = dtv_tab[(size_t)flat * 64 + tid];
        }
        {
            const unsigned short* xrow = xT + ((size_t)b * 1024 + h * 64) * 2048;
            int p = tid >> 4, tq = tid & 15;
#pragma unroll
            for (int pi = 0; pi < 4; pi++, p += 16) {
                if (d == 0) {
                    ushort4 v = *(const ushort4*)(xrow + (size_t)p * 2048 + c * 64 + tq * 4);
                    *(ushort4*)&CnXt[p * 80 + tq * 4] = v;
                } else {
                    int base = SEQLEN - 64 - c * 64;
                    ushort4 v = *(const ushort4*)(xrow + (size_t)p * 2048 + base + (15 - tq) * 4);
                    CnXt[p * 80 + tq * 4 + 0] = v.w;
                    CnXt[p * 80 + tq * 4 + 1] = v.z;
                    CnXt[p * 80 + tq * 4 + 2] = v.y;
                    CnXt[p * 80 + tq * 4 + 3] = v.x;
                }
            }
        }
        __syncthreads();
        {
            int s = tid & 63, tq = tid >> 6;
            float cs = cum_l[s], dv = dtv_l[s];
#pragma unroll
            for (int j = 0; j < 16; j++) {
                int t = tq * 16 + j;
                float g = Gm[s * 68 + t];
                float m = (s <= t) ? g * expf(cum_l[t] - cs) * dv : 0.f;
                BnMt[t * 80 + s] = f2bf(m);
            }
        }
        __syncthreads();
        {
            f32x4 acc[4] = {};
            const int mrow = wave * 16 + (lane & 15);
            const int kq = (lane >> 4) * 8;
#pragma unroll
            for (int k0 = 0; k0 < 64; k0 += 32) {
                bf16x8 afr = *(const bf16x8*)&BnMt[mrow * 80 + k0 + kq];
#pragma unroll
                for (int ni = 0; ni < 4; ni++) {
                    bf16x8 bfr = *(const bf16x8*)&CnXt[(ni * 16 + (lane & 15)) * 80 + k0 + kq];
                    acc[ni] = __builtin_amdgcn_mfma_f32_16x16x32_bf16(afr, bfr, acc[ni], 0, 0, 0);
                }
            }
            float* ybuf = d ? y_bw : y_fw;
            int quad = lane >> 4, col0 = lane & 15;
#pragma unroll
            for (int r = 0; r < 4; r++) {
                int tl = wave * 16 + quad * 4 + r;
                int tg = tglob(d, c, tl);
                int tout = d ? (tg - 1) : (tg + 1);
                if (tout >= 0 && tout < SEQLEN) {
                    float* yp = ybuf + (size_t)(b * SEQLEN + tout) * D_INNER + h * 64;
#pragma unroll
                    for (int ni = 0; ni < 4; ni++)
                        yp[ni * 16 + col0] = acc[ni][r];
                }
            }
        }
    }
}

// ---------------- K2: per-chunk state S'[p][n] via MFMA -> bf16 tiles ----------------
// S'[p][n] = sum_s XwT[p][s] * B_T[n][s]; XwT staged from xT with w(s) scaling.
__global__ __launch_bounds__(256) void ssd_state_mfma(const unsigned short* __restrict__ xbc,
                                                      const unsigned short* __restrict__ xT,
                                                      const float* __restrict__ cum_tab,
                                                      const float* __restrict__ dtv_tab,
                                                      unsigned short* __restrict__ sreg16)
{
    const int flat = blockIdx.x;
    const int c = flat & 31, h = (flat >> 5) & 15, b = (flat >> 9) & 3, d = flat >> 11;
    const int tid = threadIdx.x, wave = tid >> 6, lane = tid & 63;

    __shared__ unsigned short Xs[64 * 72];   // XwT[p][s]
    __shared__ unsigned short Bs[64 * 72];   // B_T[n][s]
    __shared__ float cum_l[64], dtv_l[64];

    if (tid < 64) {
        cum_l[tid] = cum_tab[(size_t)flat * 64 + tid];
        dtv_l[tid] = dtv_tab[(size_t)flat * 64 + tid];
    }
    // B_T staging (scattered, like intra)
    {
        int s = tid >> 2, nq = (tid & 3) * 16;
        int tg = tglob(d, c, s);
        const unsigned short* row = xbc + (size_t)(b * SEQLEN + tg) * CONV_DIM + 1024;
#pragma unroll
        for (int k = 0; k < 16; k += 4) {
            ushort4 vb = *(const ushort4*)(row + nq + k);
            Bs[(nq + k + 0) * 72 + s] = vb.x;
            Bs[(nq + k + 1) * 72 + s] = vb.y;
            Bs[(nq + k + 2) * 72 + s] = vb.z;
            Bs[(nq + k + 3) * 72 + s] = vb.w;
        }
    }
    __syncthreads();   // cum_l/dtv_l visible
    // XwT staging with w(s) = exp(cum_63 - cum_s) * dtv_s applied in fp32
    {
        const float clast = cum_l[63];
        const unsigned short* xrow = xT + ((size_t)b * 1024 + h * 64) * 2048;
        int p = tid >> 4, tq = tid & 15;
#pragma unroll
        for (int pi = 0; pi < 4; pi++, p += 16) {
            ushort4 v;
            if (d == 0) {
                v = *(const ushort4*)(xrow + (size_t)p * 2048 + c * 64 + tq * 4);
            } else {
                int base = SEQLEN - 64 - c * 64;
                ushort4 t = *(const ushort4*)(xrow + (size_t)p * 2048 + base + (15 - tq) * 4);
                v.x = t.w; v.y = t.z; v.z = t.y; v.w = t.x;
            }
            int s0 = tq * 4;
            Xs[p * 72 + s0 + 0] = f2bf(bf2f(v.x) * expf(clast - cum_l[s0 + 0]) * dtv_l[s0 + 0]);
            Xs[p * 72 + s0 + 1] = f2bf(bf2f(v.y) * expf(clast - cum_l[s0 + 1]) * dtv_l[s0 + 1]);
            Xs[p * 72 + s0 + 2] = f2bf(bf2f(v.z) * expf(clast - cum_l[s0 + 2]) * dtv_l[s0 + 2]);
            Xs[p * 72 + s0 + 3] = f2bf(bf2f(v.w) * expf(clast - cum_l[s0 + 3]) * dtv_l[s0 + 3]);
        }
    }
    __syncthreads();
    // S'[p][n]: wave = p-tile, 4 n-tiles
    f32x4 acc[4] = {};
    const int fr = lane & 15, kq = (lane >> 4) * 8;
    const int mrow = wave * 16 + fr;
#pragma unroll
    for (int k0 = 0; k0 < 64; k0 += 32) {
        bf16x8 afr = *(const bf16x8*)&Xs[mrow * 72 + k0 + kq];
#pragma unroll
        for (int ni = 0; ni < 4; ni++) {
            bf16x8 bfr = *(const bf16x8*)&Bs[(ni * 16 + fr) * 72 + k0 + kq];
            acc[ni] = __builtin_amdgcn_mfma_f32_16x16x32_bf16(afr, bfr, acc[ni], 0, 0, 0);
        }
    }
    unsigned short* st = sreg16 + (size_t)flat * 4096;
    int quad = lane >> 4, col0 = lane & 15;
#pragma unroll
    for (int r = 0; r < 4; r++) {
        int p = wave * 16 + quad * 4 + r;
#pragma unroll
        for (int ni = 0; ni < 4; ni++)
            st[(size_t)p * 64 + ni * 16 + col0] = f2bf(acc[ni][r]);
    }
}

// ---------------- K3: serial chunk scan ----------------
__global__ __launch_bounds__(256) void ssd_chunkscan_kernel(const float* __restrict__ cum_tab,
                                                            unsigned short* __restrict__ sreg16)
{
    const int ps = blockIdx.x & 3;
    const int g  = blockIdx.x >> 2;
    const int tid = threadIdx.x;
    const int base = g * 32;
    const size_t off = (size_t)ps * 1024 + tid * 4;
    float h0 = 0.f, h1 = 0.f, h2 = 0.f, h3 = 0.f;
    ushort4 s = *(ushort4*)(sreg16 + (size_t)base * 4096 + off);
    for (int c = 0; c < 32; c++) {
        int flat = base + c;
        ushort4 snext;
        if (c < 31) snext = *(ushort4*)(sreg16 + (size_t)(flat + 1) * 4096 + off);
        float dec = expf(cum_tab[(size_t)flat * 64 + 63]);
        ushort4 o;
        o.x = f2bf(h0); o.y = f2bf(h1); o.z = f2bf(h2); o.w = f2bf(h3);
        *(ushort4*)(sreg16 + (size_t)flat * 4096 + off) = o;
        h0 = h0 * dec + bf2f(s.x);
        h1 = h1 * dec + bf2f(s.y);
        h2 = h2 * dec + bf2f(s.z);
        h3 = h3 * dec + bf2f(s.w);
        s = snext;
    }
}

// ---------------- K4: inter-chunk, MFMA ----------------
__global__ __launch_bounds__(256) void ssd_inter_mfma(const unsigned short* __restrict__ xbc,
                                                      const float* __restrict__ cum_tab,
                                                      const unsigned short* __restrict__ sreg16,
                                                      float* __restrict__ y_fw,
                                                      float* __restrict__ y_bw)
{
    const int flat = blockIdx.x;
    const int c = flat & 31;
    if (c == 0) return;
    const int h = (flat >> 5) & 15, b = (flat >> 9) & 3, d = flat >> 11;
    const int tid = threadIdx.x, wave = tid >> 6, lane = tid & 63;

    __shared__ unsigned short Cs[64 * 72];
    __shared__ unsigned short Hs[64 * 72];
    __shared__ float cum_l[64];

    if (tid < 64) cum_l[tid] = cum_tab[(size_t)flat * 64 + tid];
    {
        int s = tid >> 2, nq = (tid & 3) * 16;
        int tg = tglob(d, c, s);
        const unsigned short* row = xbc + (size_t)(b * SEQLEN + tg) * CONV_DIM + 1088;
        const unsigned short* st = sreg16 + (size_t)flat * 4096 + s * 64;
#pragma unroll
        for (int k = 0; k < 16; k += 4) {
            *(ushort4*)&Cs[s * 72 + nq + k] = *(const ushort4*)(row + nq + k);
            *(ushort4*)&Hs[s * 72 + nq + k] = *(const ushort4*)(st + nq + k);
        }
    }
    __syncthreads();
    f32x4 acc[4] = {};
    const int fr = lane & 15, kq = (lane >> 4) * 8;
    const int mrow = wave * 16 + fr;
#pragma unroll
    for (int k0 = 0; k0 < 64; k0 += 32) {
        bf16x8 afr = *(const bf16x8*)&Cs[mrow * 72 + k0 + kq];
#pragma unroll
        for (int ni = 0; ni < 4; ni++) {
            bf16x8 bfr = *(const bf16x8*)&Hs[(ni * 16 + fr) * 72 + k0 + kq];
            acc[ni] = __builtin_amdgcn_mfma_f32_16x16x32_bf16(afr, bfr, acc[ni], 0, 0, 0);
        }
    }
    float* ybuf = d ? y_bw : y_fw;
    int quad = lane >> 4, col0 = lane & 15;
#pragma unroll
    for (int r = 0; r < 4; r++) {
        int tl = wave * 16 + quad * 4 + r;
        float a = expf(cum_l[tl]);
        int tg = tglob(d, c, tl);
        int tout = d ? (tg - 1) : (tg + 1);
        if (tout >= 0 && tout < SEQLEN) {
            float* yp = ybuf + (size_t)(b * SEQLEN + tout) * D_INNER + h * 64;
#pragma unroll
            for (int ni = 0; ni < 4; ni++)
                yp[ni * 16 + col0] += acc[ni][r] * a;
        }
    }
}

// ---------------- combine -> bf16 yg ----------------
__global__ __launch_bounds__(256) void combine_kernel(const unsigned short* __restrict__ zx,
                                                      const unsigned short* __restrict__ xbc,
                                                      const float* __restrict__ y_fw,
                                                      const float* __restrict__ y_bw,
                                                      const float* __restrict__ Dp,
                                                      const float* __restrict__ rms_w,
                                                      unsigned short* __restrict__ yg)
{
    int row = blockIdx.x;
    int i = threadIdx.x * 4;
    float4 yf = *(const float4*)(y_fw + (size_t)row * D_INNER + i);
    float4 yb = *(const float4*)(y_bw + (size_t)row * D_INNER + i);
    ushort4 uxs = *(const ushort4*)(xbc + (size_t)row * CONV_DIM + i);
    ushort4 uz  = *(const ushort4*)(zx + (size_t)row * D_IN_PROJ + i);
    float dp = Dp[i >> 6];
    float g[4];
    g[0] = (yf.x + yb.x + bf2f(uxs.x) * dp) * siluf(bf2f(uz.x));
    g[1] = (yf.y + yb.y + bf2f(uxs.y) * dp) * siluf(bf2f(uz.y));
    g[2] = (yf.z + yb.z + bf2f(uxs.z) * dp) * siluf(bf2f(uz.z));
    g[3] = (yf.w + yb.w + bf2f(uxs.w) * dp) * siluf(bf2f(uz.w));
    float ss = g[0]*g[0] + g[1]*g[1] + g[2]*g[2] + g[3]*g[3];
#pragma unroll
    for (int m = 1; m < 64; m <<= 1) ss += __shfl_xor(ss, m, 64);
    __shared__ float red[4];
    if ((threadIdx.x & 63) == 0) red[threadIdx.x >> 6] = ss;
    __syncthreads();
    ss = red[0] + red[1] + red[2] + red[3];
    float scale = rsqrtf(ss * (1.f / D_INNER) + EPS);
    float4 rw = *(const float4*)(rms_w + i);
    ushort4 o;
    o.x = f2bf(g[0] * scale * rw.x); o.y = f2bf(g[1] * scale * rw.y);
    o.z = f2bf(g[2] * scale * rw.z); o.w = f2bf(g[3] * scale * rw.w);
    *(ushort4*)(yg + (size_t)row * D_INNER + i) = o;
}

// ---------------- launch ----------------
extern "C" void kernel_launch(void* const* d_in, const int* in_sizes, int n_in,
                              void* d_out, int out_size, void* d_ws, size_t ws_size,
                              hipStream_t stream)
{
    const float* x         = (const float*)d_in[0];
    const float* ln1_w     = (const float*)d_in[1];
    const float* ln1_b     = (const float*)d_in[2];
    const float* in_proj_w = (const float*)d_in[3];
    const float* conv_w    = (const float*)d_in[4];
    const float* conv_b    = (const float*)d_in[5];
    const float* dt_bias   = (const float*)d_in[6];
    const float* A_log     = (const float*)d_in[7];
    const float* Dp        = (const float*)d_in[8];
    const float* rms_w     = (const float*)d_in[9];
    const float* out_proj_w= (const float*)d_in[10];
    const float* ln2_w     = (const float*)d_in[11];
    const float* ln2_b     = (const float*)d_in[12];
    const float* fc1_w     = (const float*)d_in[13];
    const float* fc1_b     = (const float*)d_in[14];
    const float* fc2_w     = (const float*)d_in[15];
    const float* fc2_b     = (const float*)d_in[16];
    float* out = (float*)d_out;

    float* ws0 = (float*)d_ws;
    unsigned short* zx_bf  = (unsigned short*)ws0;
    unsigned short* xbc_bf = (unsigned short*)(ws0 + OFF_XBCB);
    unsigned short* xT_bf  = (unsigned short*)(ws0 + OFF_XT);
    float* y_fw = ws0 + OFF_YFW;
    float* y_bw = ws0 + OFF_YBW;
    float* sreg = ws0 + OFF_SREG;
    unsigned short* sreg16 = (unsigned short*)sreg;
    unsigned short* hA_bf = (unsigned short*)sreg;
    unsigned short* yg_bf = (unsigned short*)(sreg + 2686976);
    float* x_res          = sreg + 6881280;
    unsigned short* sh    = (unsigned short*)sreg;
    unsigned short* P_in  = sh + 22151168;
    unsigned short* P_out = sh + 23330816;
    unsigned short* P_f1  = sh + 23855104;
    unsigned short* P_f2  = sh + 24903680;
    unsigned short* f1_bf = (unsigned short*)ws0;
    float* cum_tab = out;
    float* dtv_tab = out + 262144;
    float* dtf     = out + 524288;

    // 0. all weight conversions, one launch
    wconv_all<<<dim3(3712), dim3(256), 0, stream>>>(in_proj_w, P_in, out_proj_w, P_out, fc1_w, P_f1, fc2_w, P_f2);
    // 1. LN1 -> bf16
    ln_kernel<<<dim3(NTOK / 4), dim3(256), 0, stream>>>(x, ln1_w, ln1_b, hA_bf, NTOK);
    // 2. in_proj -> bf16 zx (+ fp32 dt sidecar)
    gemm_bf16<<<dim3(64, 18), dim3(256), 0, stream>>>(hA_bf, P_in, 512, 2208, nullptr, zx_bf, nullptr, nullptr, 0, dtf);
    // 3. conv (register-tiled 4c x 8t)
    conv_kernel<<<dim3(288 * 1024 / 256), dim3(256), 0, stream>>>(zx_bf, conv_w, conv_b, xbc_bf);
    // 4. transpose
    xpose_kernel<<<dim3(32, 16, 4), dim3(256), 0, stream>>>(xbc_bf, xT_bf);
    // 5. tables
    dt_table_kernel<<<dim3(1024), dim3(256), 0, stream>>>(dtf, dt_bias, A_log, cum_tab, dtv_tab);
    // 6. SSD (intra zeroes boundary rows)
    ssd_intra_mfma<<<dim3(1024), dim3(256), 0, stream>>>(xbc_bf, xT_bf, cum_tab, dtv_tab, y_fw, y_bw);
    ssd_state_mfma<<<dim3(4096), dim3(256), 0, stream>>>(xbc_bf, xT_bf, cum_tab, dtv_tab, sreg16);
    ssd_chunkscan_kernel<<<dim3(512), dim3(256), 0, stream>>>(cum_tab, sreg16);
    ssd_inter_mfma<<<dim3(4096), dim3(256), 0, stream>>>(xbc_bf, cum_tab, sreg16, y_fw, y_bw);
    // 7. combine -> bf16 yg
    combine_kernel<<<dim3(NTOK), dim3(256), 0, stream>>>(zx_bf, xbc_bf, y_fw, y_bw, Dp, rms_w, yg_bf);
    // 8. out_proj + residual(x) -> x_res
    gemm_bf16_t64<<<dim3(128, 8), dim3(256), 0, stream>>>(yg_bf, P_out, 1024, 512, x_res, nullptr, x);
    // 9. LN2 -> bf16
    ln_kernel<<<dim3(NTOK / 4), dim3(256), 0, stream>>>(x_res, ln2_w, ln2_b, hA_bf, NTOK);
    // 10. fc1 + bias + GELU -> bf16
    gemm_bf16<<<dim3(64, 16), dim3(256), 0, stream>>>(hA_bf, P_f1, 512, 2048, nullptr, f1_bf, fc1_b, nullptr, 1, nullptr);
    // 11. fc2 + bias + residual(x_res) -> out
    gemm_bf16_t64<<<dim3(128, 8), dim3(256), 0, stream>>>(f1_bf, P_f2, 2048, 512, out, fc2_b, x_res);
}